// Round 1
// baseline (1238.980 us; speedup 1.0000x reference)
//
#include <hip/hip_runtime.h>
#include <hip/hip_bf16.h>

#define BATCH 16384
#define NMOD 3
#define HEADS 8
#define DDK 32
#define DMODEL 256
#define NQKV 768
#define NCLASS 5
#define LN_EPS 1e-6f

#define BM 128
#define BN 128
#define BKK 32

struct QkvArgs {
    const float* x;
    const float* w[3][3];   // [proj q/k/v][modality]
    const float* b[3][3];
    float* out[3];          // Q, K, V each [BATCH][3][256]
};

// ---------------------------------------------------------------------------
// K1: fused QKV projection GEMM.  grid (BATCH/BM, 6, 3), block 256
// For modality z: C = X[:, off:off+d] @ W[d,256] + bias, written into Q/K/V.
// ---------------------------------------------------------------------------
__global__ __launch_bounds__(256) void qkv_gemm(QkvArgs args, int ldx) {
    const int mz = blockIdx.z;                       // modality
    const int Kdim = (mz == 0) ? 2000 : (mz == 1 ? 500 : 400);
    const int xoff = (mz == 0) ? 0 : (mz == 1 ? 2000 : 2500);
    const int by   = blockIdx.y;                     // 0..5
    const int proj = by >> 1;                        // 0=q 1=k 2=v
    const int nbase = (by & 1) * BN;                 // 0 or 128 within the 256 cols
    const int row0 = blockIdx.x * BM;

    const float* __restrict__ Xp = args.x;
    const float* __restrict__ Wp = args.w[proj][mz];
    const float* __restrict__ bias = args.b[proj][mz];
    float* __restrict__ outp = args.out[proj];

    __shared__ float As[BKK][BM + 4];   // A stored transposed [k][row]
    __shared__ float Bs[BKK][BN + 4];

    const int tid = threadIdx.x;
    const int tx = tid & 15;
    const int ty = tid >> 4;

    float acc[8][8];
#pragma unroll
    for (int i = 0; i < 8; ++i)
#pragma unroll
        for (int j = 0; j < 8; ++j) acc[i][j] = 0.f;

    const int nk = (Kdim + BKK - 1) / BKK;
    for (int kt = 0; kt < nk; ++kt) {
        const int k0 = kt * BKK;
        // stage A (transposed): rows of X tile, 4 consecutive k per thread
        {
            const int r  = tid >> 3;          // 0..31
            const int kq = (tid & 7) * 4;     // 0..28
            const int gk = k0 + kq;
#pragma unroll
            for (int it = 0; it < 4; ++it) {
                const int row = r + it * 32;
                float4 v = make_float4(0.f, 0.f, 0.f, 0.f);
                if (gk < Kdim)   // all K dims divisible by 4 -> quad all-or-nothing
                    v = *reinterpret_cast<const float4*>(
                        &Xp[(size_t)(row0 + row) * ldx + xoff + gk]);
                As[kq + 0][row] = v.x;
                As[kq + 1][row] = v.y;
                As[kq + 2][row] = v.z;
                As[kq + 3][row] = v.w;
            }
        }
        // stage B: [BKK][BN]
        {
            const int kk = tid >> 5;          // 0..7
            const int n4 = (tid & 31) * 4;    // 0..124
#pragma unroll
            for (int it = 0; it < 4; ++it) {
                const int krow = kk + it * 8;
                const int gk = k0 + krow;
                float4 v = make_float4(0.f, 0.f, 0.f, 0.f);
                if (gk < Kdim)
                    v = *reinterpret_cast<const float4*>(&Wp[(size_t)gk * 256 + nbase + n4]);
                *reinterpret_cast<float4*>(&Bs[krow][n4]) = v;
            }
        }
        __syncthreads();
#pragma unroll 8
        for (int k = 0; k < BKK; ++k) {
            float4 a0 = *reinterpret_cast<float4*>(&As[k][ty * 4]);
            float4 a1 = *reinterpret_cast<float4*>(&As[k][ty * 4 + 64]);
            float4 b0 = *reinterpret_cast<float4*>(&Bs[k][tx * 4]);
            float4 b1 = *reinterpret_cast<float4*>(&Bs[k][tx * 4 + 64]);
            float av[8] = {a0.x, a0.y, a0.z, a0.w, a1.x, a1.y, a1.z, a1.w};
            float bv[8] = {b0.x, b0.y, b0.z, b0.w, b1.x, b1.y, b1.z, b1.w};
#pragma unroll
            for (int i = 0; i < 8; ++i)
#pragma unroll
                for (int j = 0; j < 8; ++j)
                    acc[i][j] = fmaf(av[i], bv[j], acc[i][j]);
        }
        __syncthreads();
    }

    // epilogue: + bias, write into Q/K/V [BATCH][3][256]
#pragma unroll
    for (int rh = 0; rh < 2; ++rh) {
#pragma unroll
        for (int i = 0; i < 4; ++i) {
            const int row = row0 + rh * 64 + ty * 4 + i;
            const size_t ob = (size_t)row * NQKV + mz * 256 + nbase;
#pragma unroll
            for (int ch = 0; ch < 2; ++ch) {
                const int c = ch * 64 + tx * 4;
                float4 o;
                o.x = acc[rh * 4 + i][ch * 4 + 0] + bias[nbase + c + 0];
                o.y = acc[rh * 4 + i][ch * 4 + 1] + bias[nbase + c + 1];
                o.z = acc[rh * 4 + i][ch * 4 + 2] + bias[nbase + c + 2];
                o.w = acc[rh * 4 + i][ch * 4 + 3] + bias[nbase + c + 3];
                *reinterpret_cast<float4*>(&outp[ob + c]) = o;
            }
        }
    }
}

// ---------------------------------------------------------------------------
// K2: per-sample attention.  grid BATCH, block 256.
// scores -> (global-min scale + L1 norm cancel) -> softmax(s/Sum|s|) -> PV
// ---------------------------------------------------------------------------
__global__ __launch_bounds__(256) void attn_kernel(const float* __restrict__ Q,
                                                   const float* __restrict__ K,
                                                   const float* __restrict__ V,
                                                   float* __restrict__ O) {
    const int s = blockIdx.x;
    const int t = threadIdx.x;
    __shared__ float qs[NQKV], ks[NQKV], vs[NQKV];
    __shared__ float att[HEADS][3][3];

    const size_t base = (size_t)s * NQKV;
    for (int i = t; i < NQKV; i += 256) {
        qs[i] = Q[base + i];
        ks[i] = K[base + i];
        vs[i] = V[base + i];
    }
    __syncthreads();

    if (t < 72) {
        const int h = t / 9, ij = t % 9, i = ij / 3, j = ij % 3;
        const float* qp = &qs[i * 256 + h * 32];
        const float* kp = &ks[j * 256 + h * 32];
        float sc = 0.f;
#pragma unroll
        for (int d = 0; d < DDK; ++d) sc = fmaf(qp[d], kp[d], sc);
        att[h][i][j] = sc;
    }
    __syncthreads();
    if (t < 24) {
        const int h = t / 3, i = t % 3;
        float s0 = att[h][i][0], s1 = att[h][i][1], s2 = att[h][i][2];
        float r = fabsf(s0) + fabsf(s1) + fabsf(s2);
        r = fmaxf(r, 1e-12f);
        float p0 = s0 / r, p1 = s1 / r, p2 = s2 / r;
        float mx = fmaxf(p0, fmaxf(p1, p2));
        float e0 = __expf(p0 - mx), e1 = __expf(p1 - mx), e2 = __expf(p2 - mx);
        // use precise expf for safety:
        e0 = expf(p0 - mx); e1 = expf(p1 - mx); e2 = expf(p2 - mx);
        float inv = 1.f / (e0 + e1 + e2);
        att[h][i][0] = e0 * inv;
        att[h][i][1] = e1 * inv;
        att[h][i][2] = e2 * inv;
    }
    __syncthreads();

    const int c = t;            // 0..255 = h*32+d
    const int h = c >> 5;
#pragma unroll
    for (int m = 0; m < 3; ++m) {
        float o = att[h][m][0] * vs[c] + att[h][m][1] * vs[256 + c] + att[h][m][2] * vs[512 + c];
        O[base + m * 256 + c] = o;
    }
}

// ---------------------------------------------------------------------------
// K3: fc GEMM + bias + residual.  A[49152,256] @ W[256,256].
// grid (49152/BM, 2), block 256
// ---------------------------------------------------------------------------
__global__ __launch_bounds__(256) void fc_gemm(const float* __restrict__ A,
                                               const float* __restrict__ W,
                                               const float* __restrict__ bias,
                                               const float* __restrict__ resid,
                                               float* __restrict__ X) {
    const int row0 = blockIdx.x * BM;
    const int nbase = blockIdx.y * BN;

    __shared__ float As[BKK][BM + 4];
    __shared__ float Bs[BKK][BN + 4];

    const int tid = threadIdx.x;
    const int tx = tid & 15;
    const int ty = tid >> 4;

    float acc[8][8];
#pragma unroll
    for (int i = 0; i < 8; ++i)
#pragma unroll
        for (int j = 0; j < 8; ++j) acc[i][j] = 0.f;

    for (int k0 = 0; k0 < 256; k0 += BKK) {
        {
            const int r  = tid >> 3;
            const int kq = (tid & 7) * 4;
#pragma unroll
            for (int it = 0; it < 4; ++it) {
                const int row = r + it * 32;
                float4 v = *reinterpret_cast<const float4*>(
                    &A[(size_t)(row0 + row) * 256 + k0 + kq]);
                As[kq + 0][row] = v.x;
                As[kq + 1][row] = v.y;
                As[kq + 2][row] = v.z;
                As[kq + 3][row] = v.w;
            }
        }
        {
            const int kk = tid >> 5;
            const int n4 = (tid & 31) * 4;
#pragma unroll
            for (int it = 0; it < 4; ++it) {
                const int krow = kk + it * 8;
                *reinterpret_cast<float4*>(&Bs[krow][n4]) =
                    *reinterpret_cast<const float4*>(&W[(size_t)(k0 + krow) * 256 + nbase + n4]);
            }
        }
        __syncthreads();
#pragma unroll 8
        for (int k = 0; k < BKK; ++k) {
            float4 a0 = *reinterpret_cast<float4*>(&As[k][ty * 4]);
            float4 a1 = *reinterpret_cast<float4*>(&As[k][ty * 4 + 64]);
            float4 b0 = *reinterpret_cast<float4*>(&Bs[k][tx * 4]);
            float4 b1 = *reinterpret_cast<float4*>(&Bs[k][tx * 4 + 64]);
            float av[8] = {a0.x, a0.y, a0.z, a0.w, a1.x, a1.y, a1.z, a1.w};
            float bv[8] = {b0.x, b0.y, b0.z, b0.w, b1.x, b1.y, b1.z, b1.w};
#pragma unroll
            for (int i = 0; i < 8; ++i)
#pragma unroll
                for (int j = 0; j < 8; ++j)
                    acc[i][j] = fmaf(av[i], bv[j], acc[i][j]);
        }
        __syncthreads();
    }

#pragma unroll
    for (int rh = 0; rh < 2; ++rh) {
#pragma unroll
        for (int i = 0; i < 4; ++i) {
            const int row = row0 + rh * 64 + ty * 4 + i;
#pragma unroll
            for (int ch = 0; ch < 2; ++ch) {
                const int c = ch * 64 + tx * 4;
                const size_t off = (size_t)row * 256 + nbase + c;
                float4 rv = *reinterpret_cast<const float4*>(&resid[off]);
                float4 o;
                o.x = acc[rh * 4 + i][ch * 4 + 0] + bias[nbase + c + 0] + rv.x;
                o.y = acc[rh * 4 + i][ch * 4 + 1] + bias[nbase + c + 1] + rv.y;
                o.z = acc[rh * 4 + i][ch * 4 + 2] + bias[nbase + c + 2] + rv.z;
                o.w = acc[rh * 4 + i][ch * 4 + 3] + bias[nbase + c + 3] + rv.w;
                *reinterpret_cast<float4*>(&X[off]) = o;
            }
        }
    }
}

// ---------------------------------------------------------------------------
// K4: LayerNorm (per 256-chunk) + out projection [768]x[768,5]. grid BATCH.
// ---------------------------------------------------------------------------
__global__ __launch_bounds__(256) void ln_out_kernel(const float* __restrict__ X,
                                                     const float* __restrict__ g,
                                                     const float* __restrict__ bb,
                                                     const float* __restrict__ ow,
                                                     const float* __restrict__ ob,
                                                     float* __restrict__ out) {
    const int s = blockIdx.x;
    const int t = threadIdx.x;
    const int lane = t & 63, wv = t >> 6;
    __shared__ float xr[NQKV];
    __shared__ float red1[4], red2[4];
    __shared__ float cpart[4][NCLASS];

    const size_t base = (size_t)s * NQKV;
    const float gg = g[t];
    const float bbv = bb[t];

    for (int m = 0; m < 3; ++m) {
        float v = X[base + m * 256 + t];
        float s1 = v, s2 = v * v;
#pragma unroll
        for (int off = 32; off > 0; off >>= 1) {
            s1 += __shfl_down(s1, off);
            s2 += __shfl_down(s2, off);
        }
        if (lane == 0) { red1[wv] = s1; red2[wv] = s2; }
        __syncthreads();
        const float tot  = red1[0] + red1[1] + red1[2] + red1[3];
        const float tot2 = red2[0] + red2[1] + red2[2] + red2[3];
        const float mu = tot * (1.f / 256.f);
        const float var = tot2 * (1.f / 256.f) - mu * mu;
        const float inv = 1.0f / sqrtf(var + LN_EPS);
        xr[m * 256 + t] = (v - mu) * inv * gg + bbv;
        __syncthreads();
    }

    float p[NCLASS] = {0.f, 0.f, 0.f, 0.f, 0.f};
    for (int i = t; i < NQKV; i += 256) {
        const float xv = xr[i];
#pragma unroll
        for (int c = 0; c < NCLASS; ++c) p[c] = fmaf(xv, ow[i * NCLASS + c], p[c]);
    }
#pragma unroll
    for (int c = 0; c < NCLASS; ++c) {
        float pv = p[c];
#pragma unroll
        for (int off = 32; off > 0; off >>= 1) pv += __shfl_down(pv, off);
        if (lane == 0) cpart[wv][c] = pv;
    }
    __syncthreads();
    if (t < NCLASS)
        out[(size_t)s * NCLASS + t] =
            cpart[0][t] + cpart[1][t] + cpart[2][t] + cpart[3][t] + ob[t];
}

// ---------------------------------------------------------------------------
extern "C" void kernel_launch(void* const* d_in, const int* in_sizes, int n_in,
                              void* d_out, int out_size, void* d_ws, size_t ws_size,
                              hipStream_t stream) {
    const float* x = (const float*)d_in[0];
    QkvArgs qa;
    qa.x = x;
    int idx = 1;
    for (int p = 0; p < 3; ++p)
        for (int m = 0; m < 3; ++m) {
            qa.w[p][m] = (const float*)d_in[idx++];
            qa.b[p][m] = (const float*)d_in[idx++];
        }
    const float* fc_w = (const float*)d_in[19];
    const float* fc_b = (const float*)d_in[20];
    const float* ln_g = (const float*)d_in[21];
    const float* ln_b = (const float*)d_in[22];
    const float* out_w = (const float*)d_in[23];
    const float* out_b = (const float*)d_in[24];

    float* ws = (float*)d_ws;
    const size_t SZ = (size_t)BATCH * NQKV;
    float* Q = ws;
    float* Kb = ws + SZ;
    float* Vb = ws + 2 * SZ;
    float* O = ws + 3 * SZ;
    float* X = Q;  // reuse Q buffer after attention

    qa.out[0] = Q; qa.out[1] = Kb; qa.out[2] = Vb;

    dim3 g1(BATCH / BM, 6, 3);
    qkv_gemm<<<g1, 256, 0, stream>>>(qa, 2900);

    attn_kernel<<<BATCH, 256, 0, stream>>>(Q, Kb, Vb, O);

    dim3 g3((BATCH * 3) / BM, 2);
    fc_gemm<<<g3, 256, 0, stream>>>(O, fc_w, fc_b, Vb, X);

    ln_out_kernel<<<BATCH, 256, 0, stream>>>(X, ln_g, ln_b, out_w, out_b, (float*)d_out);
}

// Round 4
// 804.329 us; speedup vs baseline: 1.5404x; 1.5404x over previous
//
#include <hip/hip_runtime.h>
#include <hip/hip_bf16.h>

#define BATCH 16384
#define HEADS 8
#define DDK 32
#define NQKV 768
#define NCLASS 5
#define LN_EPS 1e-6f

#define BM 128
#define BN 128
#define BKK 32

typedef short bf16x8 __attribute__((ext_vector_type(8)));
typedef float f32x4 __attribute__((ext_vector_type(4)));

__device__ __forceinline__ unsigned short f2bf(float x) {
    unsigned u = __float_as_uint(x);
    u += 0x7fff + ((u >> 16) & 1);          // round-to-nearest-even
    return (unsigned short)(u >> 16);
}
__device__ __forceinline__ float bf2f(unsigned short b) {
    return __uint_as_float(((unsigned)b) << 16);
}

__device__ __forceinline__ void gl16(const unsigned short* g, unsigned short* l) {
    __builtin_amdgcn_global_load_lds(
        (const __attribute__((address_space(1))) unsigned int*)g,
        (__attribute__((address_space(3))) unsigned int*)l, 16, 0, 0);
}

// ---------------------------------------------------------------------------
// convert X rows [r0, r0+nrows) of modality slice -> A [nrows][2*Kpad] bf16 hi|lo
// ---------------------------------------------------------------------------
__global__ __launch_bounds__(256) void convert_x(const float* __restrict__ X,
                                                 unsigned short* __restrict__ A,
                                                 int Kdim, int Kpad, int xoff,
                                                 int r0, int nrows) {
    const int k8n = Kpad >> 3;
    const int total = nrows * k8n;
    for (int i = blockIdx.x * blockDim.x + threadIdx.x; i < total;
         i += gridDim.x * blockDim.x) {
        const int rl = i / k8n;
        const int k8 = (i - rl * k8n) << 3;
        const float* src = X + (size_t)(r0 + rl) * 2900 + xoff + k8;
        float xv[8];
        if (k8 + 8 <= Kdim) {
            float4 v0 = *reinterpret_cast<const float4*>(src);
            float4 v1 = *reinterpret_cast<const float4*>(src + 4);
            xv[0] = v0.x; xv[1] = v0.y; xv[2] = v0.z; xv[3] = v0.w;
            xv[4] = v1.x; xv[5] = v1.y; xv[6] = v1.z; xv[7] = v1.w;
        } else {
#pragma unroll
            for (int j = 0; j < 8; ++j) xv[j] = (k8 + j < Kdim) ? src[j] : 0.f;
        }
        union { unsigned short s[8]; uint4 v; } hi, lo;
#pragma unroll
        for (int j = 0; j < 8; ++j) {
            hi.s[j] = f2bf(xv[j]);
            lo.s[j] = f2bf(xv[j] - bf2f(hi.s[j]));
        }
        unsigned short* dst = A + (size_t)rl * (2 * Kpad) + k8;
        *reinterpret_cast<uint4*>(dst) = hi.v;
        *reinterpret_cast<uint4*>(dst + Kpad) = lo.v;
    }
}

// ---------------------------------------------------------------------------
// convert W (q|k|v each [Kdim][256]) -> Bt [768][2*Kpad] bf16 hi|lo (N-major),
// plus bias_ext[768]
// ---------------------------------------------------------------------------
__global__ __launch_bounds__(256) void convert_w(
    const float* __restrict__ wq, const float* __restrict__ wk,
    const float* __restrict__ wv, const float* __restrict__ bq,
    const float* __restrict__ bk, const float* __restrict__ bv,
    unsigned short* __restrict__ Bt, float* __restrict__ bias,
    int Kdim, int Kpad) {
    const int gid0 = blockIdx.x * blockDim.x + threadIdx.x;
    if (gid0 < NQKV) {
        const int p = gid0 >> 8, c = gid0 & 255;
        bias[gid0] = (p == 0 ? bq : p == 1 ? bk : bv)[c];
    }
    const int k8n = Kpad >> 3;
    const int total = NQKV * k8n;
    for (int i = gid0; i < total; i += gridDim.x * blockDim.x) {
        const int kb = i / NQKV;
        const int n = i - kb * NQKV;
        const int k8 = kb << 3;
        const int p = n >> 8, c = n & 255;
        const float* wsrc = (p == 0 ? wq : p == 1 ? wk : wv);
        union { unsigned short s[8]; uint4 v; } hi, lo;
#pragma unroll
        for (int j = 0; j < 8; ++j) {
            float x = (k8 + j < Kdim) ? wsrc[(size_t)(k8 + j) * 256 + c] : 0.f;
            hi.s[j] = f2bf(x);
            lo.s[j] = f2bf(x - bf2f(hi.s[j]));
        }
        unsigned short* dst = Bt + (size_t)n * (2 * Kpad) + k8;
        *reinterpret_cast<uint4*>(dst) = hi.v;
        *reinterpret_cast<uint4*>(dst + Kpad) = lo.v;
    }
}

// ---------------------------------------------------------------------------
// K1: bf16x3 MFMA GEMM, single K-pass, 3 products per K-tile.
// grid (nrows/128, 6), block 256 (4 waves, each 64x64 out).
// ---------------------------------------------------------------------------
__global__ __launch_bounds__(256) void qkv_mfma(
    const unsigned short* __restrict__ A,   // [nrows][2*Kpad] (chunk-local)
    const unsigned short* __restrict__ Bt,  // [768][2*Kpad]
    const float* __restrict__ bias,         // [768]
    float* __restrict__ Qo, float* __restrict__ Ko, float* __restrict__ Vo,
    int Kpad, int mz, int r0) {
    const int ld = 2 * Kpad;
    const int row0l = blockIdx.x * BM;      // chunk-local row base
    const int nb = blockIdx.y * BN;
    const int tid = threadIdx.x;
    const int lane = tid & 63;
    const int w = tid >> 6;
    const int wr = w >> 1, wc = w & 1;

    __shared__ alignas(16) unsigned short AsH[BM * BKK];
    __shared__ alignas(16) unsigned short AsL[BM * BKK];
    __shared__ alignas(16) unsigned short BsH[BN * BKK];
    __shared__ alignas(16) unsigned short BsL[BN * BKK];

    f32x4 acc[4][4];
#pragma unroll
    for (int i = 0; i < 4; ++i)
#pragma unroll
        for (int j = 0; j < 4; ++j) acc[i][j] = (f32x4){0.f, 0.f, 0.f, 0.f};

    // staging: wave w covers rows [w*16,(w+1)*16) and [(w+4)*16,(w+5)*16)
    // lane l -> row +(l>>2), k elems (l&3)*8..+8  (contiguous 1 KiB per call)
    const int rs = lane >> 2;
    const int kk = (lane & 3) * 8;
    const size_t gA0 = (size_t)(row0l + w * 16 + rs) * ld + kk;
    const size_t gA1 = (size_t)(row0l + (w + 4) * 16 + rs) * ld + kk;
    const size_t gB0 = (size_t)(nb + w * 16 + rs) * ld + kk;
    const size_t gB1 = (size_t)(nb + (w + 4) * 16 + rs) * ld + kk;
    unsigned short* lAH0 = &AsH[w * 512];
    unsigned short* lAH1 = &AsH[(w + 4) * 512];
    unsigned short* lAL0 = &AsL[w * 512];
    unsigned short* lAL1 = &AsL[(w + 4) * 512];
    unsigned short* lBH0 = &BsH[w * 512];
    unsigned short* lBH1 = &BsH[(w + 4) * 512];
    unsigned short* lBL0 = &BsL[w * 512];
    unsigned short* lBL1 = &BsL[(w + 4) * 512];

    // fragment read offsets (A: row=lane&15, k-block=(lane>>4)*8)
    const int fr = lane & 15;
    const int fk = (lane >> 4) * 8;
    const int aoff0 = (wr * 64 + fr) * BKK + fk;
    const int boff0 = (wc * 64 + fr) * BKK + fk;

    const int nk = Kpad >> 5;
#pragma unroll 1
    for (int kt = 0; kt < nk; ++kt) {
        const int k0 = kt * BKK;
        __syncthreads();                       // prev compute done before overwrite
        gl16(A + gA0 + k0, lAH0);
        gl16(A + gA1 + k0, lAH1);
        gl16(A + Kpad + gA0 + k0, lAL0);
        gl16(A + Kpad + gA1 + k0, lAL1);
        gl16(Bt + gB0 + k0, lBH0);
        gl16(Bt + gB1 + k0, lBH1);
        gl16(Bt + Kpad + gB0 + k0, lBL0);
        gl16(Bt + Kpad + gB1 + k0, lBL1);
        __syncthreads();                       // staged (vmcnt drained by barrier)

        bf16x8 ah[4], bh[4];
#pragma unroll
        for (int mi = 0; mi < 4; ++mi)
            ah[mi] = *reinterpret_cast<const bf16x8*>(&AsH[aoff0 + mi * 16 * BKK]);
#pragma unroll
        for (int ni = 0; ni < 4; ++ni)
            bh[ni] = *reinterpret_cast<const bf16x8*>(&BsH[boff0 + ni * 16 * BKK]);
#pragma unroll
        for (int mi = 0; mi < 4; ++mi)
#pragma unroll
            for (int ni = 0; ni < 4; ++ni)
                acc[mi][ni] = __builtin_amdgcn_mfma_f32_16x16x32_bf16(
                    ah[mi], bh[ni], acc[mi][ni], 0, 0, 0);
        {
            bf16x8 al[4];
#pragma unroll
            for (int mi = 0; mi < 4; ++mi)
                al[mi] = *reinterpret_cast<const bf16x8*>(&AsL[aoff0 + mi * 16 * BKK]);
#pragma unroll
            for (int mi = 0; mi < 4; ++mi)
#pragma unroll
                for (int ni = 0; ni < 4; ++ni)
                    acc[mi][ni] = __builtin_amdgcn_mfma_f32_16x16x32_bf16(
                        al[mi], bh[ni], acc[mi][ni], 0, 0, 0);
        }
        {
            bf16x8 bl[4];
#pragma unroll
            for (int ni = 0; ni < 4; ++ni)
                bl[ni] = *reinterpret_cast<const bf16x8*>(&BsL[boff0 + ni * 16 * BKK]);
#pragma unroll
            for (int mi = 0; mi < 4; ++mi)
#pragma unroll
                for (int ni = 0; ni < 4; ++ni)
                    acc[mi][ni] = __builtin_amdgcn_mfma_f32_16x16x32_bf16(
                        ah[mi], bl[ni], acc[mi][ni], 0, 0, 0);
        }
    }

    // epilogue: C/D layout col=lane&15, row=(lane>>4)*4+j  (m89-verified)
#pragma unroll
    for (int ni = 0; ni < 4; ++ni) {
        const int gc = nb + wc * 64 + ni * 16 + fr;
        const int proj = gc >> 8;
        const int col = gc & 255;
        const float bv = bias[gc];
        float* outp = (proj == 0 ? Qo : proj == 1 ? Ko : Vo);
#pragma unroll
        for (int mi = 0; mi < 4; ++mi) {
            const int gr = r0 + row0l + wr * 64 + mi * 16 + (lane >> 4) * 4;
            float* p = outp + (size_t)gr * NQKV + mz * 256 + col;
#pragma unroll
            for (int j = 0; j < 4; ++j)
                p[(size_t)j * NQKV] = acc[mi][ni][j] + bv;
        }
    }
}

// ---------------------------------------------------------------------------
// K2: per-sample attention (global-min scale + TEMP cancel in L1 norm).
// NOTE: O may alias K — each block reads its sample's K into LDS before
// writing O for that same sample only.
// ---------------------------------------------------------------------------
__global__ __launch_bounds__(256) void attn_kernel(const float* __restrict__ Q,
                                                   const float* __restrict__ K,
                                                   const float* __restrict__ V,
                                                   float* __restrict__ O) {
    const int s = blockIdx.x;
    const int t = threadIdx.x;
    __shared__ float qs[NQKV], ks[NQKV], vs[NQKV];
    __shared__ float att[HEADS][3][3];

    const size_t base = (size_t)s * NQKV;
    for (int i = t; i < NQKV; i += 256) {
        qs[i] = Q[base + i];
        ks[i] = K[base + i];
        vs[i] = V[base + i];
    }
    __syncthreads();

    if (t < 72) {
        const int h = t / 9, ij = t % 9, i = ij / 3, j = ij % 3;
        const float* qp = &qs[i * 256 + h * 32];
        const float* kp = &ks[j * 256 + h * 32];
        float sc = 0.f;
#pragma unroll
        for (int d = 0; d < DDK; ++d) sc = fmaf(qp[d], kp[d], sc);
        att[h][i][j] = sc;
    }
    __syncthreads();
    if (t < 24) {
        const int h = t / 3, i = t % 3;
        float s0 = att[h][i][0], s1 = att[h][i][1], s2 = att[h][i][2];
        float r = fabsf(s0) + fabsf(s1) + fabsf(s2);
        r = fmaxf(r, 1e-12f);
        float p0 = s0 / r, p1 = s1 / r, p2 = s2 / r;
        float mx = fmaxf(p0, fmaxf(p1, p2));
        float e0 = expf(p0 - mx), e1 = expf(p1 - mx), e2 = expf(p2 - mx);
        float inv = 1.f / (e0 + e1 + e2);
        att[h][i][0] = e0 * inv;
        att[h][i][1] = e1 * inv;
        att[h][i][2] = e2 * inv;
    }
    __syncthreads();

    const int c = t;
    const int h = c >> 5;
#pragma unroll
    for (int m = 0; m < 3; ++m) {
        float o = att[h][m][0] * vs[c] + att[h][m][1] * vs[256 + c] + att[h][m][2] * vs[512 + c];
        O[base + m * 256 + c] = o;
    }
}

// ---------------------------------------------------------------------------
// K3: fc GEMM + bias + residual (fp32).  A[49152,256] @ W[256,256].
// ---------------------------------------------------------------------------
__global__ __launch_bounds__(256) void fc_gemm(const float* __restrict__ A,
                                               const float* __restrict__ W,
                                               const float* __restrict__ bias,
                                               const float* __restrict__ resid,
                                               float* __restrict__ X) {
    const int row0 = blockIdx.x * BM;
    const int nbase = blockIdx.y * BN;

    __shared__ float As[BKK][BM + 4];
    __shared__ float Bs[BKK][BN + 4];

    const int tid = threadIdx.x;
    const int tx = tid & 15;
    const int ty = tid >> 4;

    float acc[8][8];
#pragma unroll
    for (int i = 0; i < 8; ++i)
#pragma unroll
        for (int j = 0; j < 8; ++j) acc[i][j] = 0.f;

    for (int k0 = 0; k0 < 256; k0 += BKK) {
        {
            const int r = tid >> 3;
            const int kq = (tid & 7) * 4;
#pragma unroll
            for (int it = 0; it < 4; ++it) {
                const int row = r + it * 32;
                float4 v = *reinterpret_cast<const float4*>(
                    &A[(size_t)(row0 + row) * 256 + k0 + kq]);
                As[kq + 0][row] = v.x;
                As[kq + 1][row] = v.y;
                As[kq + 2][row] = v.z;
                As[kq + 3][row] = v.w;
            }
        }
        {
            const int kkk = tid >> 5;
            const int n4 = (tid & 31) * 4;
#pragma unroll
            for (int it = 0; it < 4; ++it) {
                const int krow = kkk + it * 8;
                *reinterpret_cast<float4*>(&Bs[krow][n4]) =
                    *reinterpret_cast<const float4*>(&W[(size_t)(k0 + krow) * 256 + nbase + n4]);
            }
        }
        __syncthreads();
#pragma unroll 8
        for (int k = 0; k < BKK; ++k) {
            float4 a0 = *reinterpret_cast<float4*>(&As[k][ty * 4]);
            float4 a1 = *reinterpret_cast<float4*>(&As[k][ty * 4 + 64]);
            float4 b0 = *reinterpret_cast<float4*>(&Bs[k][tx * 4]);
            float4 b1 = *reinterpret_cast<float4*>(&Bs[k][tx * 4 + 64]);
            float av[8] = {a0.x, a0.y, a0.z, a0.w, a1.x, a1.y, a1.z, a1.w};
            float bv[8] = {b0.x, b0.y, b0.z, b0.w, b1.x, b1.y, b1.z, b1.w};
#pragma unroll
            for (int i = 0; i < 8; ++i)
#pragma unroll
                for (int j = 0; j < 8; ++j)
                    acc[i][j] = fmaf(av[i], bv[j], acc[i][j]);
        }
        __syncthreads();
    }

#pragma unroll
    for (int rh = 0; rh < 2; ++rh) {
#pragma unroll
        for (int i = 0; i < 4; ++i) {
            const int row = row0 + rh * 64 + ty * 4 + i;
#pragma unroll
            for (int ch = 0; ch < 2; ++ch) {
                const int c = ch * 64 + tx * 4;
                const size_t off = (size_t)row * 256 + nbase + c;
                float4 rv = *reinterpret_cast<const float4*>(&resid[off]);
                float4 o;
                o.x = acc[rh * 4 + i][ch * 4 + 0] + bias[nbase + c + 0] + rv.x;
                o.y = acc[rh * 4 + i][ch * 4 + 1] + bias[nbase + c + 1] + rv.y;
                o.z = acc[rh * 4 + i][ch * 4 + 2] + bias[nbase + c + 2] + rv.z;
                o.w = acc[rh * 4 + i][ch * 4 + 3] + bias[nbase + c + 3] + rv.w;
                *reinterpret_cast<float4*>(&X[off]) = o;
            }
        }
    }
}

// ---------------------------------------------------------------------------
// K4: LayerNorm (per 256-chunk) + out projection [768]x[768,5].
// ---------------------------------------------------------------------------
__global__ __launch_bounds__(256) void ln_out_kernel(const float* __restrict__ X,
                                                     const float* __restrict__ g,
                                                     const float* __restrict__ bb,
                                                     const float* __restrict__ ow,
                                                     const float* __restrict__ ob,
                                                     float* __restrict__ out) {
    const int s = blockIdx.x;
    const int t = threadIdx.x;
    const int lane = t & 63, wv = t >> 6;
    __shared__ float xr[NQKV];
    __shared__ float red1[4], red2[4];
    __shared__ float cpart[4][NCLASS];

    const size_t base = (size_t)s * NQKV;
    const float gg = g[t];
    const float bbv = bb[t];

    for (int m = 0; m < 3; ++m) {
        float v = X[base + m * 256 + t];
        float s1 = v, s2 = v * v;
#pragma unroll
        for (int off = 32; off > 0; off >>= 1) {
            s1 += __shfl_down(s1, off);
            s2 += __shfl_down(s2, off);
        }
        if (lane == 0) { red1[wv] = s1; red2[wv] = s2; }
        __syncthreads();
        const float tot = red1[0] + red1[1] + red1[2] + red1[3];
        const float tot2 = red2[0] + red2[1] + red2[2] + red2[3];
        const float mu = tot * (1.f / 256.f);
        const float var = tot2 * (1.f / 256.f) - mu * mu;
        const float inv = 1.0f / sqrtf(var + LN_EPS);
        xr[m * 256 + t] = (v - mu) * inv * gg + bbv;
        __syncthreads();
    }

    float p[NCLASS] = {0.f, 0.f, 0.f, 0.f, 0.f};
    for (int i = t; i < NQKV; i += 256) {
        const float xv = xr[i];
#pragma unroll
        for (int c = 0; c < NCLASS; ++c) p[c] = fmaf(xv, ow[i * NCLASS + c], p[c]);
    }
#pragma unroll
    for (int c = 0; c < NCLASS; ++c) {
        float pv = p[c];
#pragma unroll
        for (int off = 32; off > 0; off >>= 1) pv += __shfl_down(pv, off);
        if (lane == 0) cpart[wv][c] = pv;
    }
    __syncthreads();
    if (t < NCLASS)
        out[(size_t)s * NCLASS + t] =
            cpart[0][t] + cpart[1][t] + cpart[2][t] + cpart[3][t] + ob[t];
}

// ---------------------------------------------------------------------------
extern "C" void kernel_launch(void* const* d_in, const int* in_sizes, int n_in,
                              void* d_out, int out_size, void* d_ws, size_t ws_size,
                              hipStream_t stream) {
    const float* x = (const float*)d_in[0];
    const float* wq[3] = {(const float*)d_in[1], (const float*)d_in[3], (const float*)d_in[5]};
    const float* bq[3] = {(const float*)d_in[2], (const float*)d_in[4], (const float*)d_in[6]};
    const float* wk[3] = {(const float*)d_in[7], (const float*)d_in[9], (const float*)d_in[11]};
    const float* bk[3] = {(const float*)d_in[8], (const float*)d_in[10], (const float*)d_in[12]};
    const float* wvv[3] = {(const float*)d_in[13], (const float*)d_in[15], (const float*)d_in[17]};
    const float* bv[3] = {(const float*)d_in[14], (const float*)d_in[16], (const float*)d_in[18]};
    const float* fc_w = (const float*)d_in[19];
    const float* fc_b = (const float*)d_in[20];
    const float* ln_g = (const float*)d_in[21];
    const float* ln_b = (const float*)d_in[22];
    const float* out_w = (const float*)d_in[23];
    const float* out_b = (const float*)d_in[24];

    float* ws = (float*)d_ws;
    const size_t SZ = (size_t)BATCH * NQKV;          // floats per Q/K/V buffer
    float* Q = ws;
    float* Kb = ws + SZ;
    float* Vb = ws + 2 * SZ;
    float* biasx = ws + 3 * SZ;                      // 768 floats
    unsigned short* Bt = (unsigned short*)(biasx + NQKV);       // 768*4096 shorts max
    unsigned short* Aext = Bt + (size_t)NQKV * 4096;

    // adaptive batch chunking so A_ext fits whatever ws_size we actually have
    const size_t fixed_bytes = (3 * SZ + NQKV) * sizeof(float) +
                               (size_t)NQKV * 4096 * sizeof(unsigned short);
    size_t avail = (ws_size > fixed_bytes) ? ws_size - fixed_bytes : 0;
    size_t rc = (avail / (4096 * sizeof(unsigned short))) & ~(size_t)127;
    if (rc < 128) rc = 128;                          // ws_size >= ~160MB guaranteed in practice
    if (rc > BATCH) rc = BATCH;
    const int rows_chunk = (int)rc;

    float* O = Kb;   // alias: K dead after attn (attn reads K to LDS before writing O)
    float* X = Q;    // alias: Q dead after attn

    const int Kdim[3] = {2000, 500, 400};
    const int Kpad[3] = {2048, 512, 448};
    const int xoff[3] = {0, 2000, 2500};

    for (int m = 0; m < 3; ++m) {
        convert_w<<<768, 256, 0, stream>>>(wq[m], wk[m], wvv[m], bq[m], bk[m], bv[m],
                                           Bt, biasx, Kdim[m], Kpad[m]);
        for (int r0 = 0; r0 < BATCH; r0 += rows_chunk) {
            const int nr = (BATCH - r0 < rows_chunk) ? (BATCH - r0) : rows_chunk;
            const int cgrid = ((nr * (Kpad[m] >> 3)) + 255) / 256;
            convert_x<<<(cgrid < 2048 ? cgrid : 2048), 256, 0, stream>>>(
                x, Aext, Kdim[m], Kpad[m], xoff[m], r0, nr);
            dim3 g(nr / BM, NQKV / BN);
            qkv_mfma<<<g, 256, 0, stream>>>(Aext, Bt, biasx, Q, Kb, Vb, Kpad[m], m, r0);
        }
    }

    attn_kernel<<<BATCH, 256, 0, stream>>>(Q, Kb, Vb, O);

    dim3 g3((BATCH * 3) / BM, 2);
    fc_gemm<<<g3, 256, 0, stream>>>(O, fc_w, fc_b, Vb, X);

    ln_out_kernel<<<BATCH, 256, 0, stream>>>(X, ln_g, ln_b, out_w, out_b, (float*)d_out);
}

// Round 5
// 733.678 us; speedup vs baseline: 1.6887x; 1.0963x over previous
//
#include <hip/hip_runtime.h>
#include <hip/hip_bf16.h>

#define BATCH 16384
#define HEADS 8
#define DDK 32
#define NQKV 768
#define NCLASS 5
#define LN_EPS 1e-6f

#define BM 128
#define BN 128
#define BKK 32

typedef _Float16 f16x8 __attribute__((ext_vector_type(8)));
typedef float f32x4 __attribute__((ext_vector_type(4)));

__device__ __forceinline__ void gl16(const void* g, void* l) {
    __builtin_amdgcn_global_load_lds(
        (const __attribute__((address_space(1))) unsigned int*)g,
        (__attribute__((address_space(3))) unsigned int*)l, 16, 0, 0);
}

// ---------------------------------------------------------------------------
// convert X rows [r0, r0+nrows) of modality slice -> A [nrows][2*Kpad] f16 hi|lo
// ---------------------------------------------------------------------------
__global__ __launch_bounds__(256) void convert_x(const float* __restrict__ X,
                                                 _Float16* __restrict__ A,
                                                 int Kdim, int Kpad, int xoff,
                                                 int r0, int nrows) {
    const int k8n = Kpad >> 3;
    const int total = nrows * k8n;
    for (int i = blockIdx.x * blockDim.x + threadIdx.x; i < total;
         i += gridDim.x * blockDim.x) {
        const int rl = i / k8n;
        const int k8 = (i - rl * k8n) << 3;
        const float* src = X + (size_t)(r0 + rl) * 2900 + xoff + k8;
        float xv[8];
        if (k8 + 8 <= Kdim) {
            float4 v0 = *reinterpret_cast<const float4*>(src);
            float4 v1 = *reinterpret_cast<const float4*>(src + 4);
            xv[0] = v0.x; xv[1] = v0.y; xv[2] = v0.z; xv[3] = v0.w;
            xv[4] = v1.x; xv[5] = v1.y; xv[6] = v1.z; xv[7] = v1.w;
        } else {
#pragma unroll
            for (int j = 0; j < 8; ++j) xv[j] = (k8 + j < Kdim) ? src[j] : 0.f;
        }
        union { _Float16 h[8]; uint4 v; } hi, lo;
#pragma unroll
        for (int j = 0; j < 8; ++j) {
            hi.h[j] = (_Float16)xv[j];
            lo.h[j] = (_Float16)(xv[j] - (float)hi.h[j]);
        }
        _Float16* dst = A + (size_t)rl * (2 * Kpad) + k8;
        *reinterpret_cast<uint4*>(dst) = hi.v;
        *reinterpret_cast<uint4*>(dst + Kpad) = lo.v;
    }
}

// ---------------------------------------------------------------------------
// convert ALL weights once: qkv (hi-only, N-major) + fc_w (hi-only, N-major)
// grid (768, 4): y=0..2 -> modality y, y=3 -> fc_w
// ---------------------------------------------------------------------------
struct WArgs {
    const float* w[3][3];   // [proj][modality]
    const float* b[3][3];
    const float* fcw;
    _Float16* Bt;           // [3][768][2048] (row stride Kpad[m], tight)
    float* biasx;           // [3][768]
    _Float16* fcWh;         // [256][256] N-major
};

__global__ __launch_bounds__(256) void convert_w_all(WArgs a) {
    const int y = blockIdx.y;
    const int gid = blockIdx.x * 256 + threadIdx.x;
    if (y < 3) {
        const int m = y;
        const int Kdim = (m == 0) ? 2000 : (m == 1 ? 500 : 400);
        const int Kpad = (m == 0) ? 2048 : (m == 1 ? 512 : 448);
        if (gid < NQKV) {
            const int p = gid >> 8, c = gid & 255;
            a.biasx[m * NQKV + gid] = a.b[p][m][c];
        }
        const int k8n = Kpad >> 3;
        const int total = NQKV * k8n;
        _Float16* dst0 = a.Bt + (size_t)m * NQKV * 2048;
        for (int i = gid; i < total; i += gridDim.x * 256) {
            const int kb = i / NQKV;
            const int n = i - kb * NQKV;
            const int k8 = kb << 3;
            const int p = n >> 8, c = n & 255;
            const float* wsrc = a.w[p][m];
            union { _Float16 h[8]; uint4 v; } hi;
#pragma unroll
            for (int j = 0; j < 8; ++j) {
                float x = (k8 + j < Kdim) ? wsrc[(size_t)(k8 + j) * 256 + c] : 0.f;
                hi.h[j] = (_Float16)x;
            }
            *reinterpret_cast<uint4*>(dst0 + (size_t)n * Kpad + k8) = hi.v;
        }
    } else {
        // fc_w [256][256] -> fcWh [n][k]
        for (int i = gid; i < 256 * 32; i += gridDim.x * 256) {
            const int n = i & 255;
            const int k8 = (i >> 8) << 3;
            union { _Float16 h[8]; uint4 v; } hi;
#pragma unroll
            for (int j = 0; j < 8; ++j)
                hi.h[j] = (_Float16)a.fcw[(size_t)(k8 + j) * 256 + n];
            *reinterpret_cast<uint4*>(a.fcWh + (size_t)n * 256 + k8) = hi.v;
        }
    }
}

// ---------------------------------------------------------------------------
// K1: f16x2 MFMA GEMM (2 products: Ah*Bh + Al*Bh), per-modality.
// grid (nrows/128, 6), block 256 (4 waves, each 64x64 out).
// ---------------------------------------------------------------------------
__global__ __launch_bounds__(256) void qkv_mfma(
    const _Float16* __restrict__ A,    // [nrows][2*Kpad] (chunk-local)
    const _Float16* __restrict__ Bt,   // [768][Kpad] hi only
    const float* __restrict__ bias,    // [768]
    float* __restrict__ Qo, float* __restrict__ Ko, float* __restrict__ Vo,
    int Kpad, int mz, int r0) {
    const int ld = 2 * Kpad;
    const int row0l = blockIdx.x * BM;
    const int nb = blockIdx.y * BN;
    const int tid = threadIdx.x;
    const int lane = tid & 63;
    const int w = tid >> 6;
    const int wr = w >> 1, wc = w & 1;

    __shared__ alignas(16) _Float16 AsH[BM * BKK];
    __shared__ alignas(16) _Float16 AsL[BM * BKK];
    __shared__ alignas(16) _Float16 BsH[BN * BKK];

    f32x4 acc[4][4];
#pragma unroll
    for (int i = 0; i < 4; ++i)
#pragma unroll
        for (int j = 0; j < 4; ++j) acc[i][j] = (f32x4){0.f, 0.f, 0.f, 0.f};

    // staging: lane l -> row +(l>>2), k elems (l&3)*8..+8 (contiguous 1 KiB/call)
    const int rs = lane >> 2;
    const int kk = (lane & 3) * 8;
    const size_t gA0 = (size_t)(row0l + w * 16 + rs) * ld + kk;
    const size_t gA1 = (size_t)(row0l + (w + 4) * 16 + rs) * ld + kk;
    const size_t gB0 = (size_t)(nb + w * 16 + rs) * Kpad + kk;
    const size_t gB1 = (size_t)(nb + (w + 4) * 16 + rs) * Kpad + kk;
    _Float16* lAH0 = &AsH[w * 512];
    _Float16* lAH1 = &AsH[(w + 4) * 512];
    _Float16* lAL0 = &AsL[w * 512];
    _Float16* lAL1 = &AsL[(w + 4) * 512];
    _Float16* lBH0 = &BsH[w * 512];
    _Float16* lBH1 = &BsH[(w + 4) * 512];

    // fragment read offsets (row=lane&15, k-block=(lane>>4)*8) — m89-verified geometry
    const int fr = lane & 15;
    const int fk = (lane >> 4) * 8;
    const int aoff0 = (wr * 64 + fr) * BKK + fk;
    const int boff0 = (wc * 64 + fr) * BKK + fk;

    const int nk = Kpad >> 5;
#pragma unroll 1
    for (int kt = 0; kt < nk; ++kt) {
        const int k0 = kt * BKK;
        __syncthreads();                       // prev compute done before overwrite
        gl16(A + gA0 + k0, lAH0);
        gl16(A + gA1 + k0, lAH1);
        gl16(A + Kpad + gA0 + k0, lAL0);
        gl16(A + Kpad + gA1 + k0, lAL1);
        gl16(Bt + gB0 + k0, lBH0);
        gl16(Bt + gB1 + k0, lBH1);
        __syncthreads();                       // staged (vmcnt drained by barrier)

        f16x8 ah[4], bh[4];
#pragma unroll
        for (int mi = 0; mi < 4; ++mi)
            ah[mi] = *reinterpret_cast<const f16x8*>(&AsH[aoff0 + mi * 16 * BKK]);
#pragma unroll
        for (int ni = 0; ni < 4; ++ni)
            bh[ni] = *reinterpret_cast<const f16x8*>(&BsH[boff0 + ni * 16 * BKK]);
#pragma unroll
        for (int mi = 0; mi < 4; ++mi)
#pragma unroll
            for (int ni = 0; ni < 4; ++ni)
                acc[mi][ni] = __builtin_amdgcn_mfma_f32_16x16x32_f16(
                    ah[mi], bh[ni], acc[mi][ni], 0, 0, 0);
        {
            f16x8 al[4];
#pragma unroll
            for (int mi = 0; mi < 4; ++mi)
                al[mi] = *reinterpret_cast<const f16x8*>(&AsL[aoff0 + mi * 16 * BKK]);
#pragma unroll
            for (int mi = 0; mi < 4; ++mi)
#pragma unroll
                for (int ni = 0; ni < 4; ++ni)
                    acc[mi][ni] = __builtin_amdgcn_mfma_f32_16x16x32_f16(
                        al[mi], bh[ni], acc[mi][ni], 0, 0, 0);
        }
    }

    // epilogue: C/D layout col=lane&15, row=(lane>>4)*4+j  (m89-verified)
#pragma unroll
    for (int ni = 0; ni < 4; ++ni) {
        const int gc = nb + wc * 64 + ni * 16 + fr;
        const int proj = gc >> 8;
        const int col = gc & 255;
        const float bv = bias[gc];
        float* outp = (proj == 0 ? Qo : proj == 1 ? Ko : Vo);
#pragma unroll
        for (int mi = 0; mi < 4; ++mi) {
            const int gr = r0 + row0l + wr * 64 + mi * 16 + (lane >> 4) * 4;
            float* p = outp + (size_t)gr * NQKV + mz * 256 + col;
#pragma unroll
            for (int j = 0; j < 4; ++j)
                p[(size_t)j * NQKV] = acc[mi][ni][j] + bv;
        }
    }
}

// ---------------------------------------------------------------------------
// K2: per-sample attention; writes O as f16 hi|lo planes [49152][512].
// ---------------------------------------------------------------------------
__global__ __launch_bounds__(256) void attn_kernel(const float* __restrict__ Q,
                                                   const float* __restrict__ K,
                                                   const float* __restrict__ V,
                                                   _Float16* __restrict__ Of) {
    const int s = blockIdx.x;
    const int t = threadIdx.x;
    __shared__ float qs[NQKV], ks[NQKV], vs[NQKV];
    __shared__ float att[HEADS][3][3];

    const size_t base = (size_t)s * NQKV;
    for (int i = t; i < NQKV; i += 256) {
        qs[i] = Q[base + i];
        ks[i] = K[base + i];
        vs[i] = V[base + i];
    }
    __syncthreads();

    if (t < 72) {
        const int h = t / 9, ij = t % 9, i = ij / 3, j = ij % 3;
        const float* qp = &qs[i * 256 + h * 32];
        const float* kp = &ks[j * 256 + h * 32];
        float sc = 0.f;
#pragma unroll
        for (int d = 0; d < DDK; ++d) sc = fmaf(qp[d], kp[d], sc);
        att[h][i][j] = sc;
    }
    __syncthreads();
    if (t < 24) {
        const int h = t / 3, i = t % 3;
        float s0 = att[h][i][0], s1 = att[h][i][1], s2 = att[h][i][2];
        float r = fabsf(s0) + fabsf(s1) + fabsf(s2);
        r = fmaxf(r, 1e-12f);
        float p0 = s0 / r, p1 = s1 / r, p2 = s2 / r;
        float mx = fmaxf(p0, fmaxf(p1, p2));
        float e0 = expf(p0 - mx), e1 = expf(p1 - mx), e2 = expf(p2 - mx);
        float inv = 1.f / (e0 + e1 + e2);
        att[h][i][0] = e0 * inv;
        att[h][i][1] = e1 * inv;
        att[h][i][2] = e2 * inv;
    }
    __syncthreads();

    const int c = t;
    const int h = c >> 5;
#pragma unroll
    for (int m = 0; m < 3; ++m) {
        float o = att[h][m][0] * vs[c] + att[h][m][1] * vs[256 + c] + att[h][m][2] * vs[512 + c];
        const size_t ob = ((size_t)s * 3 + m) * 512 + c;
        _Float16 oh = (_Float16)o;
        Of[ob] = oh;
        Of[ob + 256] = (_Float16)(o - (float)oh);
    }
}

// ---------------------------------------------------------------------------
// K3: fc via f16x2 MFMA + bias + residual. O[49152][512 hi|lo] @ fcWh[256][256].
// grid (384, 2), block 256.
// ---------------------------------------------------------------------------
__global__ __launch_bounds__(256) void fc_mfma(const _Float16* __restrict__ O,
                                               const _Float16* __restrict__ Wh,
                                               const float* __restrict__ fcb,
                                               const float* __restrict__ resid,
                                               float* __restrict__ X) {
    const int row0 = blockIdx.x * BM;
    const int nb = blockIdx.y * BN;
    const int tid = threadIdx.x;
    const int lane = tid & 63;
    const int w = tid >> 6;
    const int wr = w >> 1, wc = w & 1;

    __shared__ alignas(16) _Float16 AsH[BM * BKK];
    __shared__ alignas(16) _Float16 AsL[BM * BKK];
    __shared__ alignas(16) _Float16 BsH[BN * BKK];

    f32x4 acc[4][4];
#pragma unroll
    for (int i = 0; i < 4; ++i)
#pragma unroll
        for (int j = 0; j < 4; ++j) acc[i][j] = (f32x4){0.f, 0.f, 0.f, 0.f};

    const int rs = lane >> 2;
    const int kk = (lane & 3) * 8;
    const size_t gA0 = (size_t)(row0 + w * 16 + rs) * 512 + kk;
    const size_t gA1 = (size_t)(row0 + (w + 4) * 16 + rs) * 512 + kk;
    const size_t gB0 = (size_t)(nb + w * 16 + rs) * 256 + kk;
    const size_t gB1 = (size_t)(nb + (w + 4) * 16 + rs) * 256 + kk;
    _Float16* lAH0 = &AsH[w * 512];
    _Float16* lAH1 = &AsH[(w + 4) * 512];
    _Float16* lAL0 = &AsL[w * 512];
    _Float16* lAL1 = &AsL[(w + 4) * 512];
    _Float16* lBH0 = &BsH[w * 512];
    _Float16* lBH1 = &BsH[(w + 4) * 512];

    const int fr = lane & 15;
    const int fk = (lane >> 4) * 8;
    const int aoff0 = (wr * 64 + fr) * BKK + fk;
    const int boff0 = (wc * 64 + fr) * BKK + fk;

#pragma unroll 1
    for (int kt = 0; kt < 8; ++kt) {
        const int k0 = kt * BKK;
        __syncthreads();
        gl16(O + gA0 + k0, lAH0);
        gl16(O + gA1 + k0, lAH1);
        gl16(O + 256 + gA0 + k0, lAL0);
        gl16(O + 256 + gA1 + k0, lAL1);
        gl16(Wh + gB0 + k0, lBH0);
        gl16(Wh + gB1 + k0, lBH1);
        __syncthreads();

        f16x8 ah[4], bh[4];
#pragma unroll
        for (int mi = 0; mi < 4; ++mi)
            ah[mi] = *reinterpret_cast<const f16x8*>(&AsH[aoff0 + mi * 16 * BKK]);
#pragma unroll
        for (int ni = 0; ni < 4; ++ni)
            bh[ni] = *reinterpret_cast<const f16x8*>(&BsH[boff0 + ni * 16 * BKK]);
#pragma unroll
        for (int mi = 0; mi < 4; ++mi)
#pragma unroll
            for (int ni = 0; ni < 4; ++ni)
                acc[mi][ni] = __builtin_amdgcn_mfma_f32_16x16x32_f16(
                    ah[mi], bh[ni], acc[mi][ni], 0, 0, 0);
        {
            f16x8 al[4];
#pragma unroll
            for (int mi = 0; mi < 4; ++mi)
                al[mi] = *reinterpret_cast<const f16x8*>(&AsL[aoff0 + mi * 16 * BKK]);
#pragma unroll
            for (int mi = 0; mi < 4; ++mi)
#pragma unroll
                for (int ni = 0; ni < 4; ++ni)
                    acc[mi][ni] = __builtin_amdgcn_mfma_f32_16x16x32_f16(
                        al[mi], bh[ni], acc[mi][ni], 0, 0, 0);
        }
    }

#pragma unroll
    for (int ni = 0; ni < 4; ++ni) {
        const int gc = nb + wc * 64 + ni * 16 + fr;
        const float bv = fcb[gc];
#pragma unroll
        for (int mi = 0; mi < 4; ++mi) {
            const int gr = row0 + wr * 64 + mi * 16 + (lane >> 4) * 4;
#pragma unroll
            for (int j = 0; j < 4; ++j) {
                const size_t off = (size_t)(gr + j) * 256 + gc;
                X[off] = acc[mi][ni][j] + bv + resid[off];
            }
        }
    }
}

// ---------------------------------------------------------------------------
// K4: LayerNorm (per 256-chunk) + out projection [768]x[768,5].
// ---------------------------------------------------------------------------
__global__ __launch_bounds__(256) void ln_out_kernel(const float* __restrict__ X,
                                                     const float* __restrict__ g,
                                                     const float* __restrict__ bb,
                                                     const float* __restrict__ ow,
                                                     const float* __restrict__ ob,
                                                     float* __restrict__ out) {
    const int s = blockIdx.x;
    const int t = threadIdx.x;
    const int lane = t & 63, wv = t >> 6;
    __shared__ float xr[NQKV];
    __shared__ float red1[4], red2[4];
    __shared__ float cpart[4][NCLASS];

    const size_t base = (size_t)s * NQKV;
    const float gg = g[t];
    const float bbv = bb[t];

    for (int m = 0; m < 3; ++m) {
        float v = X[base + m * 256 + t];
        float s1 = v, s2 = v * v;
#pragma unroll
        for (int off = 32; off > 0; off >>= 1) {
            s1 += __shfl_down(s1, off);
            s2 += __shfl_down(s2, off);
        }
        if (lane == 0) { red1[wv] = s1; red2[wv] = s2; }
        __syncthreads();
        const float tot = red1[0] + red1[1] + red1[2] + red1[3];
        const float tot2 = red2[0] + red2[1] + red2[2] + red2[3];
        const float mu = tot * (1.f / 256.f);
        const float var = tot2 * (1.f / 256.f) - mu * mu;
        const float inv = 1.0f / sqrtf(var + LN_EPS);
        xr[m * 256 + t] = (v - mu) * inv * gg + bbv;
        __syncthreads();
    }

    float p[NCLASS] = {0.f, 0.f, 0.f, 0.f, 0.f};
    for (int i = t; i < NQKV; i += 256) {
        const float xv = xr[i];
#pragma unroll
        for (int c = 0; c < NCLASS; ++c) p[c] = fmaf(xv, ow[i * NCLASS + c], p[c]);
    }
#pragma unroll
    for (int c = 0; c < NCLASS; ++c) {
        float pv = p[c];
#pragma unroll
        for (int off = 32; off > 0; off >>= 1) pv += __shfl_down(pv, off);
        if (lane == 0) cpart[wv][c] = pv;
    }
    __syncthreads();
    if (t < NCLASS)
        out[(size_t)s * NCLASS + t] =
            cpart[0][t] + cpart[1][t] + cpart[2][t] + cpart[3][t] + ob[t];
}

// ---------------------------------------------------------------------------
extern "C" void kernel_launch(void* const* d_in, const int* in_sizes, int n_in,
                              void* d_out, int out_size, void* d_ws, size_t ws_size,
                              hipStream_t stream) {
    const float* x = (const float*)d_in[0];
    WArgs wa;
    int idx = 1;
    for (int p = 0; p < 3; ++p)
        for (int m = 0; m < 3; ++m) {
            wa.w[p][m] = (const float*)d_in[idx++];
            wa.b[p][m] = (const float*)d_in[idx++];
        }
    const float* fc_w = (const float*)d_in[19];
    const float* fc_b = (const float*)d_in[20];
    const float* ln_g = (const float*)d_in[21];
    const float* ln_b = (const float*)d_in[22];
    const float* out_w = (const float*)d_in[23];
    const float* out_b = (const float*)d_in[24];

    float* ws = (float*)d_ws;
    const size_t SZ = (size_t)BATCH * NQKV;          // floats per Q/K/V buffer
    float* Q = ws;
    float* Kb = ws + SZ;
    float* Vb = ws + 2 * SZ;
    float* biasx = ws + 3 * SZ;                      // [3][768]
    _Float16* Bt = (_Float16*)(biasx + 3 * NQKV);    // [3][768][2048] hi-only
    _Float16* fcWh = Bt + (size_t)3 * NQKV * 2048;   // [256][256]
    _Float16* pool = fcWh + 256 * 256;               // A_ext chunks, later O_f16

    wa.fcw = fc_w; wa.Bt = Bt; wa.biasx = biasx; wa.fcWh = fcWh;

    const size_t fixed_bytes = (size_t)((char*)pool - (char*)d_ws);
    const size_t avail = (ws_size > fixed_bytes) ? ws_size - fixed_bytes : 0;

    float* X = Q;    // alias: Q dead after attn
    _Float16* Of = pool;  // alias: A_ext dead after last qkv_mfma

    const int Kdim[3] = {2000, 500, 400};
    const int Kpad[3] = {2048, 512, 448};
    const int xoff[3] = {0, 2000, 2500};

    convert_w_all<<<dim3(768, 4), 256, 0, stream>>>(wa);

    for (int m = 0; m < 3; ++m) {
        // adaptive chunk: bytes per row = 2 planes * Kpad * 2B
        size_t rc = (avail / ((size_t)4 * Kpad[m])) & ~(size_t)127;
        if (rc < 128) rc = 128;
        if (rc > BATCH) rc = BATCH;
        const int rows_chunk = (int)rc;
        for (int r0 = 0; r0 < BATCH; r0 += rows_chunk) {
            const int nr = (BATCH - r0 < rows_chunk) ? (BATCH - r0) : rows_chunk;
            const int cgrid = ((nr * (Kpad[m] >> 3)) + 255) / 256;
            convert_x<<<(cgrid < 2048 ? cgrid : 2048), 256, 0, stream>>>(
                x, pool, Kdim[m], Kpad[m], xoff[m], r0, nr);
            dim3 g(nr / BM, NQKV / BN);
            qkv_mfma<<<g, 256, 0, stream>>>(pool, Bt + (size_t)m * NQKV * 2048,
                                            biasx + m * NQKV, Q, Kb, Vb,
                                            Kpad[m], m, r0);
        }
    }

    attn_kernel<<<BATCH, 256, 0, stream>>>(Q, Kb, Vb, Of);

    fc_mfma<<<dim3((BATCH * 3) / BM, 2), 256, 0, stream>>>(Of, fcWh, fc_b, Vb, X);

    ln_out_kernel<<<BATCH, 256, 0, stream>>>(X, ln_g, ln_b, out_w, out_b, (float*)d_out);
}

// Round 6
// 706.543 us; speedup vs baseline: 1.7536x; 1.0384x over previous
//
#include <hip/hip_runtime.h>
#include <hip/hip_bf16.h>

#define BATCH 16384
#define HEADS 8
#define DDK 32
#define NQKV 768
#define NCLASS 5
#define LN_EPS 1e-6f

#define BM 128
#define BN 128
#define BKK 32

typedef _Float16 f16x8 __attribute__((ext_vector_type(8)));
typedef float f32x4 __attribute__((ext_vector_type(4)));

__device__ __forceinline__ void gl16(const void* g, void* l) {
    __builtin_amdgcn_global_load_lds(
        (const __attribute__((address_space(1))) unsigned int*)g,
        (__attribute__((address_space(3))) unsigned int*)l, 16, 0, 0);
}

// ---------------------------------------------------------------------------
// Fused convert: X rows [r0, r0+nrows) -> A0 [nr][4096] (hi|lo),
// A1 [nr][1024], A2 [nr][1024].  384 k8-slots per row: 256 | 64 | 64.
// ---------------------------------------------------------------------------
__global__ __launch_bounds__(256) void convert_x_all(const float* __restrict__ X,
                                                     _Float16* __restrict__ A0,
                                                     _Float16* __restrict__ A1,
                                                     _Float16* __restrict__ A2,
                                                     int r0, int nrows) {
    const int total = nrows * 384;
    for (int i = blockIdx.x * blockDim.x + threadIdx.x; i < total;
         i += gridDim.x * blockDim.x) {
        const int rl = i / 384;
        const int slot = i - rl * 384;
        int k8, Kdim, xoff, lo_off;
        _Float16* dst;
        if (slot < 256) {
            k8 = slot << 3; Kdim = 2000; xoff = 0; lo_off = 2048;
            dst = A0 + (size_t)rl * 4096 + k8;
        } else if (slot < 320) {
            k8 = (slot - 256) << 3; Kdim = 500; xoff = 2000; lo_off = 512;
            dst = A1 + (size_t)rl * 1024 + k8;
        } else {
            k8 = (slot - 320) << 3; Kdim = 400; xoff = 2500; lo_off = 512;
            dst = A2 + (size_t)rl * 1024 + k8;
        }
        const float* src = X + (size_t)(r0 + rl) * 2900 + xoff + k8;
        float xv[8];
        if (k8 + 8 <= Kdim) {
            float4 v0 = *reinterpret_cast<const float4*>(src);
            float4 v1 = *reinterpret_cast<const float4*>(src + 4);
            xv[0] = v0.x; xv[1] = v0.y; xv[2] = v0.z; xv[3] = v0.w;
            xv[4] = v1.x; xv[5] = v1.y; xv[6] = v1.z; xv[7] = v1.w;
        } else {
#pragma unroll
            for (int j = 0; j < 8; ++j) xv[j] = (k8 + j < Kdim) ? src[j] : 0.f;
        }
        union { _Float16 h[8]; uint4 v; } hi, lo;
#pragma unroll
        for (int j = 0; j < 8; ++j) {
            hi.h[j] = (_Float16)xv[j];
            lo.h[j] = (_Float16)(xv[j] - (float)hi.h[j]);
        }
        *reinterpret_cast<uint4*>(dst) = hi.v;
        *reinterpret_cast<uint4*>(dst + lo_off) = lo.v;
    }
}

// ---------------------------------------------------------------------------
// convert weights: qkv N-major [hi|hi] per modality + fc_w hi-only N-major
// grid (768, 4): y=0..2 -> modality, y=3 -> fc_w
// ---------------------------------------------------------------------------
struct WArgs {
    const float* w[3][3];   // [proj][modality]
    const float* b[3][3];
    const float* fcw;
    _Float16* Bt;           // B0 [768][4096] | B1 [768][1024] | B2 [768][1024]
    float* biasx;           // [3][768]
    _Float16* fcWh;         // [256][256] N-major hi
};

__global__ __launch_bounds__(256) void convert_w_all(WArgs a) {
    const int y = blockIdx.y;
    const int gid = blockIdx.x * 256 + threadIdx.x;
    if (y < 3) {
        const int m = y;
        const int Kdim = (m == 0) ? 2000 : (m == 1 ? 500 : 400);
        const int Kpad = (m == 0) ? 2048 : 512;
        if (gid < NQKV) {
            const int p = gid >> 8, c = gid & 255;
            a.biasx[m * NQKV + gid] = a.b[p][m][c];
        }
        _Float16* dst0 = a.Bt;
        if (m >= 1) dst0 += (size_t)NQKV * 4096;
        if (m == 2) dst0 += (size_t)NQKV * 1024;
        const int ld = 2 * Kpad;
        const int k8n = Kpad >> 3;
        const int total = NQKV * k8n;
        for (int i = gid; i < total; i += gridDim.x * 256) {
            const int kb = i / NQKV;
            const int n = i - kb * NQKV;
            const int k8 = kb << 3;
            const int p = n >> 8, c = n & 255;
            const float* wsrc = a.w[p][m];
            union { _Float16 h[8]; uint4 v; } hi;
#pragma unroll
            for (int j = 0; j < 8; ++j) {
                float x = (k8 + j < Kdim) ? wsrc[(size_t)(k8 + j) * 256 + c] : 0.f;
                hi.h[j] = (_Float16)x;
            }
            *reinterpret_cast<uint4*>(dst0 + (size_t)n * ld + k8) = hi.v;        // hi
            *reinterpret_cast<uint4*>(dst0 + (size_t)n * ld + Kpad + k8) = hi.v; // hi dup
        }
    } else {
        for (int i = gid; i < 256 * 32; i += gridDim.x * 256) {
            const int n = i & 255;
            const int k8 = (i >> 8) << 3;
            union { _Float16 h[8]; uint4 v; } hi;
#pragma unroll
            for (int j = 0; j < 8; ++j)
                hi.h[j] = (_Float16)a.fcw[(size_t)(k8 + j) * 256 + n];
            *reinterpret_cast<uint4*>(a.fcWh + (size_t)n * 256 + k8) = hi.v;
        }
    }
}

// ---------------------------------------------------------------------------
// K1: unified-K MFMA GEMM, all 3 modalities in one dispatch.
// grid (nr/128, 6, 3), block 256 (4 waves, each 64x64 out).  m97 shape:
// per K-step {4x gl16 (16KB) | barrier | 8x ds_read_b128 + 16 MFMA | barrier}.
// ---------------------------------------------------------------------------
struct GemmArgs {
    const _Float16* A[3];   // chunk-local [nr][keff]
    const _Float16* B[3];   // [768][keff]
    int keff[3];            // 4096, 1024, 1024
};

__global__ __launch_bounds__(256) void qkv_mfma_all(
    GemmArgs ga, const float* __restrict__ biasx,
    float* __restrict__ Qo, float* __restrict__ Ko, float* __restrict__ Vo,
    int r0) {
    const int z = blockIdx.z;
    const _Float16* __restrict__ A = ga.A[z];
    const _Float16* __restrict__ Bt = ga.B[z];
    const int ld = ga.keff[z];
    const int nk = ld >> 5;
    const float* __restrict__ bias = biasx + z * NQKV;

    const int row0l = blockIdx.x * BM;
    const int nb = blockIdx.y * BN;
    const int tid = threadIdx.x;
    const int lane = tid & 63;
    const int w = tid >> 6;
    const int wr = w >> 1, wc = w & 1;

    __shared__ alignas(16) _Float16 As[BM * BKK];
    __shared__ alignas(16) _Float16 Bs[BN * BKK];

    f32x4 acc[4][4];
#pragma unroll
    for (int i = 0; i < 4; ++i)
#pragma unroll
        for (int j = 0; j < 4; ++j) acc[i][j] = (f32x4){0.f, 0.f, 0.f, 0.f};

    // staging: call c covers rows c*64 + w*16 + (lane>>2), k = (lane&3)*8
    const int rs = lane >> 2;
    const int kk = (lane & 3) * 8;
    const size_t gA0 = (size_t)(row0l + w * 16 + rs) * ld + kk;
    const size_t gA1 = gA0 + (size_t)64 * ld;
    const size_t gB0 = (size_t)(nb + w * 16 + rs) * ld + kk;
    const size_t gB1 = gB0 + (size_t)64 * ld;
    _Float16* lA0 = &As[(w * 16) * BKK];
    _Float16* lA1 = &As[(64 + w * 16) * BKK];
    _Float16* lB0 = &Bs[(w * 16) * BKK];
    _Float16* lB1 = &Bs[(64 + w * 16) * BKK];

    // fragment read offsets (row=lane&15, k-block=(lane>>4)*8) — m89-verified
    const int fr = lane & 15;
    const int fk = (lane >> 4) * 8;
    const int aoff0 = (wr * 64 + fr) * BKK + fk;
    const int boff0 = (wc * 64 + fr) * BKK + fk;

#pragma unroll 1
    for (int kt = 0; kt < nk; ++kt) {
        const int k0 = kt * BKK;
        __syncthreads();                       // prev compute done before overwrite
        gl16(A + gA0 + k0, lA0);
        gl16(A + gA1 + k0, lA1);
        gl16(Bt + gB0 + k0, lB0);
        gl16(Bt + gB1 + k0, lB1);
        __syncthreads();                       // staged (vmcnt drained by barrier)

        f16x8 a[4], b[4];
#pragma unroll
        for (int mi = 0; mi < 4; ++mi)
            a[mi] = *reinterpret_cast<const f16x8*>(&As[aoff0 + mi * 16 * BKK]);
#pragma unroll
        for (int ni = 0; ni < 4; ++ni)
            b[ni] = *reinterpret_cast<const f16x8*>(&Bs[boff0 + ni * 16 * BKK]);
#pragma unroll
        for (int mi = 0; mi < 4; ++mi)
#pragma unroll
            for (int ni = 0; ni < 4; ++ni)
                acc[mi][ni] = __builtin_amdgcn_mfma_f32_16x16x32_f16(
                    a[mi], b[ni], acc[mi][ni], 0, 0, 0);
    }

    // epilogue: C/D layout col=lane&15, row=(lane>>4)*4+j  (m89-verified)
#pragma unroll
    for (int ni = 0; ni < 4; ++ni) {
        const int gc = nb + wc * 64 + ni * 16 + fr;
        const int proj = gc >> 8;
        const int col = gc & 255;
        const float bv = bias[gc];
        float* outp = (proj == 0 ? Qo : proj == 1 ? Ko : Vo);
#pragma unroll
        for (int mi = 0; mi < 4; ++mi) {
            const int gr = r0 + row0l + wr * 64 + mi * 16 + (lane >> 4) * 4;
            float* p = outp + (size_t)gr * NQKV + z * 256 + col;
#pragma unroll
            for (int j = 0; j < 4; ++j)
                p[(size_t)j * NQKV] = acc[mi][ni][j] + bv;
        }
    }
}

// ---------------------------------------------------------------------------
// K2: per-sample attention; writes O as f16 hi|lo planes [49152][512].
// ---------------------------------------------------------------------------
__global__ __launch_bounds__(256) void attn_kernel(const float* __restrict__ Q,
                                                   const float* __restrict__ K,
                                                   const float* __restrict__ V,
                                                   _Float16* __restrict__ Of) {
    const int s = blockIdx.x;
    const int t = threadIdx.x;
    __shared__ float qs[NQKV], ks[NQKV], vs[NQKV];
    __shared__ float att[HEADS][3][3];

    const size_t base = (size_t)s * NQKV;
    for (int i = t; i < NQKV; i += 256) {
        qs[i] = Q[base + i];
        ks[i] = K[base + i];
        vs[i] = V[base + i];
    }
    __syncthreads();

    if (t < 72) {
        const int h = t / 9, ij = t % 9, i = ij / 3, j = ij % 3;
        const float* qp = &qs[i * 256 + h * 32];
        const float* kp = &ks[j * 256 + h * 32];
        float sc = 0.f;
#pragma unroll
        for (int d = 0; d < DDK; ++d) sc = fmaf(qp[d], kp[d], sc);
        att[h][i][j] = sc;
    }
    __syncthreads();
    if (t < 24) {
        const int h = t / 3, i = t % 3;
        float s0 = att[h][i][0], s1 = att[h][i][1], s2 = att[h][i][2];
        float r = fabsf(s0) + fabsf(s1) + fabsf(s2);
        r = fmaxf(r, 1e-12f);
        float p0 = s0 / r, p1 = s1 / r, p2 = s2 / r;
        float mx = fmaxf(p0, fmaxf(p1, p2));
        float e0 = expf(p0 - mx), e1 = expf(p1 - mx), e2 = expf(p2 - mx);
        float inv = 1.f / (e0 + e1 + e2);
        att[h][i][0] = e0 * inv;
        att[h][i][1] = e1 * inv;
        att[h][i][2] = e2 * inv;
    }
    __syncthreads();

    const int c = t;
    const int h = c >> 5;
#pragma unroll
    for (int m = 0; m < 3; ++m) {
        float o = att[h][m][0] * vs[c] + att[h][m][1] * vs[256 + c] + att[h][m][2] * vs[512 + c];
        const size_t ob = ((size_t)s * 3 + m) * 512 + c;
        _Float16 oh = (_Float16)o;
        Of[ob] = oh;
        Of[ob + 256] = (_Float16)(o - (float)oh);
    }
}

// ---------------------------------------------------------------------------
// K3: fc via f16x2 MFMA + bias + residual. O[49152][512 hi|lo] @ fcWh[256][256].
// ---------------------------------------------------------------------------
__global__ __launch_bounds__(256) void fc_mfma(const _Float16* __restrict__ O,
                                               const _Float16* __restrict__ Wh,
                                               const float* __restrict__ fcb,
                                               const float* __restrict__ resid,
                                               float* __restrict__ X) {
    const int row0 = blockIdx.x * BM;
    const int nb = blockIdx.y * BN;
    const int tid = threadIdx.x;
    const int lane = tid & 63;
    const int w = tid >> 6;
    const int wr = w >> 1, wc = w & 1;

    __shared__ alignas(16) _Float16 AsH[BM * BKK];
    __shared__ alignas(16) _Float16 AsL[BM * BKK];
    __shared__ alignas(16) _Float16 BsH[BN * BKK];

    f32x4 acc[4][4];
#pragma unroll
    for (int i = 0; i < 4; ++i)
#pragma unroll
        for (int j = 0; j < 4; ++j) acc[i][j] = (f32x4){0.f, 0.f, 0.f, 0.f};

    const int rs = lane >> 2;
    const int kk = (lane & 3) * 8;
    const size_t gA0 = (size_t)(row0 + w * 16 + rs) * 512 + kk;
    const size_t gA1 = (size_t)(row0 + (w + 4) * 16 + rs) * 512 + kk;
    const size_t gB0 = (size_t)(nb + w * 16 + rs) * 256 + kk;
    const size_t gB1 = (size_t)(nb + (w + 4) * 16 + rs) * 256 + kk;
    _Float16* lAH0 = &AsH[w * 512];
    _Float16* lAH1 = &AsH[(w + 4) * 512];
    _Float16* lAL0 = &AsL[w * 512];
    _Float16* lAL1 = &AsL[(w + 4) * 512];
    _Float16* lBH0 = &BsH[w * 512];
    _Float16* lBH1 = &BsH[(w + 4) * 512];

    const int fr = lane & 15;
    const int fk = (lane >> 4) * 8;
    const int aoff0 = (wr * 64 + fr) * BKK + fk;
    const int boff0 = (wc * 64 + fr) * BKK + fk;

#pragma unroll 1
    for (int kt = 0; kt < 8; ++kt) {
        const int k0 = kt * BKK;
        __syncthreads();
        gl16(O + gA0 + k0, lAH0);
        gl16(O + gA1 + k0, lAH1);
        gl16(O + 256 + gA0 + k0, lAL0);
        gl16(O + 256 + gA1 + k0, lAL1);
        gl16(Wh + gB0 + k0, lBH0);
        gl16(Wh + gB1 + k0, lBH1);
        __syncthreads();

        f16x8 ah[4], bh[4];
#pragma unroll
        for (int mi = 0; mi < 4; ++mi)
            ah[mi] = *reinterpret_cast<const f16x8*>(&AsH[aoff0 + mi * 16 * BKK]);
#pragma unroll
        for (int ni = 0; ni < 4; ++ni)
            bh[ni] = *reinterpret_cast<const f16x8*>(&BsH[boff0 + ni * 16 * BKK]);
#pragma unroll
        for (int mi = 0; mi < 4; ++mi)
#pragma unroll
            for (int ni = 0; ni < 4; ++ni)
                acc[mi][ni] = __builtin_amdgcn_mfma_f32_16x16x32_f16(
                    ah[mi], bh[ni], acc[mi][ni], 0, 0, 0);
        {
            f16x8 al[4];
#pragma unroll
            for (int mi = 0; mi < 4; ++mi)
                al[mi] = *reinterpret_cast<const f16x8*>(&AsL[aoff0 + mi * 16 * BKK]);
#pragma unroll
            for (int mi = 0; mi < 4; ++mi)
#pragma unroll
                for (int ni = 0; ni < 4; ++ni)
                    acc[mi][ni] = __builtin_amdgcn_mfma_f32_16x16x32_f16(
                        al[mi], bh[ni], acc[mi][ni], 0, 0, 0);
        }
    }

#pragma unroll
    for (int ni = 0; ni < 4; ++ni) {
        const int gc = nb + wc * 64 + ni * 16 + fr;
        const float bv = fcb[gc];
#pragma unroll
        for (int mi = 0; mi < 4; ++mi) {
            const int gr = row0 + wr * 64 + mi * 16 + (lane >> 4) * 4;
#pragma unroll
            for (int j = 0; j < 4; ++j) {
                const size_t off = (size_t)(gr + j) * 256 + gc;
                X[off] = acc[mi][ni][j] + bv + resid[off];
            }
        }
    }
}

// ---------------------------------------------------------------------------
// K4: LayerNorm (per 256-chunk) + out projection [768]x[768,5].
// ---------------------------------------------------------------------------
__global__ __launch_bounds__(256) void ln_out_kernel(const float* __restrict__ X,
                                                     const float* __restrict__ g,
                                                     const float* __restrict__ bb,
                                                     const float* __restrict__ ow,
                                                     const float* __restrict__ ob,
                                                     float* __restrict__ out) {
    const int s = blockIdx.x;
    const int t = threadIdx.x;
    const int lane = t & 63, wv = t >> 6;
    __shared__ float xr[NQKV];
    __shared__ float red1[4], red2[4];
    __shared__ float cpart[4][NCLASS];

    const size_t base = (size_t)s * NQKV;
    const float gg = g[t];
    const float bbv = bb[t];

    for (int m = 0; m < 3; ++m) {
        float v = X[base + m * 256 + t];
        float s1 = v, s2 = v * v;
#pragma unroll
        for (int off = 32; off > 0; off >>= 1) {
            s1 += __shfl_down(s1, off);
            s2 += __shfl_down(s2, off);
        }
        if (lane == 0) { red1[wv] = s1; red2[wv] = s2; }
        __syncthreads();
        const float tot = red1[0] + red1[1] + red1[2] + red1[3];
        const float tot2 = red2[0] + red2[1] + red2[2] + red2[3];
        const float mu = tot * (1.f / 256.f);
        const float var = tot2 * (1.f / 256.f) - mu * mu;
        const float inv = 1.0f / sqrtf(var + LN_EPS);
        xr[m * 256 + t] = (v - mu) * inv * gg + bbv;
        __syncthreads();
    }

    float p[NCLASS] = {0.f, 0.f, 0.f, 0.f, 0.f};
    for (int i = t; i < NQKV; i += 256) {
        const float xv = xr[i];
#pragma unroll
        for (int c = 0; c < NCLASS; ++c) p[c] = fmaf(xv, ow[i * NCLASS + c], p[c]);
    }
#pragma unroll
    for (int c = 0; c < NCLASS; ++c) {
        float pv = p[c];
#pragma unroll
        for (int off = 32; off > 0; off >>= 1) pv += __shfl_down(pv, off);
        if (lane == 0) cpart[wv][c] = pv;
    }
    __syncthreads();
    if (t < NCLASS)
        out[(size_t)s * NCLASS + t] =
            cpart[0][t] + cpart[1][t] + cpart[2][t] + cpart[3][t] + ob[t];
}

// ---------------------------------------------------------------------------
extern "C" void kernel_launch(void* const* d_in, const int* in_sizes, int n_in,
                              void* d_out, int out_size, void* d_ws, size_t ws_size,
                              hipStream_t stream) {
    const float* x = (const float*)d_in[0];
    WArgs wa;
    int idx = 1;
    for (int p = 0; p < 3; ++p)
        for (int m = 0; m < 3; ++m) {
            wa.w[p][m] = (const float*)d_in[idx++];
            wa.b[p][m] = (const float*)d_in[idx++];
        }
    const float* fc_w = (const float*)d_in[19];
    const float* fc_b = (const float*)d_in[20];
    const float* ln_g = (const float*)d_in[21];
    const float* ln_b = (const float*)d_in[22];
    const float* out_w = (const float*)d_in[23];
    const float* out_b = (const float*)d_in[24];

    float* ws = (float*)d_ws;
    const size_t SZ = (size_t)BATCH * NQKV;
    float* Q = ws;
    float* Kb = ws + SZ;
    float* Vb = ws + 2 * SZ;
    float* biasx = ws + 3 * SZ;                              // [3][768]
    _Float16* Bt = (_Float16*)(biasx + 3 * NQKV);            // 768*(4096+1024+1024)
    _Float16* fcWh = Bt + (size_t)NQKV * 6144;               // [256][256]
    _Float16* pool = fcWh + 256 * 256;

    wa.fcw = fc_w; wa.Bt = Bt; wa.biasx = biasx; wa.fcWh = fcWh;

    const size_t fixed_bytes = (size_t)((char*)pool - (char*)d_ws);
    const size_t avail = (ws_size > fixed_bytes) ? ws_size - fixed_bytes : 0;
    // per-row A bytes: (4096 + 1024 + 1024) f16 = 12288 B
    size_t rc = (avail / 12288) & ~(size_t)127;
    if (rc < 128) rc = 128;
    if (rc > BATCH) rc = BATCH;
    const int rows_chunk = (int)rc;

    float* X = Q;                 // alias: Q dead after attn
    _Float16* Of = pool;          // alias: A-pool dead after last qkv_mfma

    convert_w_all<<<dim3(768, 4), 256, 0, stream>>>(wa);

    GemmArgs ga;
    ga.keff[0] = 4096; ga.keff[1] = 1024; ga.keff[2] = 1024;
    ga.B[0] = Bt;
    ga.B[1] = Bt + (size_t)NQKV * 4096;
    ga.B[2] = Bt + (size_t)NQKV * 5120;

    _Float16* A0 = pool;
    _Float16* A1 = A0 + (size_t)rows_chunk * 4096;
    _Float16* A2 = A1 + (size_t)rows_chunk * 1024;
    ga.A[0] = A0; ga.A[1] = A1; ga.A[2] = A2;

    for (int r0 = 0; r0 < BATCH; r0 += rows_chunk) {
        const int nr = (BATCH - r0 < rows_chunk) ? (BATCH - r0) : rows_chunk;
        const int cgrid = (nr * 384 + 255) / 256;
        convert_x_all<<<(cgrid < 2048 ? cgrid : 2048), 256, 0, stream>>>(
            x, A0, A1, A2, r0, nr);
        dim3 g(nr / BM, NQKV / BN, 3);
        qkv_mfma_all<<<g, 256, 0, stream>>>(ga, biasx, Q, Kb, Vb, r0);
    }

    attn_kernel<<<BATCH, 256, 0, stream>>>(Q, Kb, Vb, Of);

    fc_mfma<<<dim3((BATCH * 3) / BM, 2), 256, 0, stream>>>(Of, fcWh, fc_b, Vb, X);

    ln_out_kernel<<<BATCH, 256, 0, stream>>>(X, ln_g, ln_b, out_w, out_b, (float*)d_out);
}

// Round 7
// 654.902 us; speedup vs baseline: 1.8919x; 1.0789x over previous
//
#include <hip/hip_runtime.h>
#include <hip/hip_bf16.h>

#define BATCH 16384
#define HEADS 8
#define DDK 32
#define NQKV 768
#define NCLASS 5
#define LN_EPS 1e-6f

#define BM 128
#define BN 128
#define BKK 32

typedef _Float16 f16x8 __attribute__((ext_vector_type(8)));
typedef float f32x4 __attribute__((ext_vector_type(4)));

__device__ __forceinline__ void gl16(const void* g, void* l) {
    __builtin_amdgcn_global_load_lds(
        (const __attribute__((address_space(1))) unsigned int*)g,
        (__attribute__((address_space(3))) unsigned int*)l, 16, 0, 0);
}

// ---------------------------------------------------------------------------
// convert weights: qkv N-major hi-only per modality + fc_w hi-only N-major
// grid (768, 4): y=0..2 -> modality, y=3 -> fc_w
// ---------------------------------------------------------------------------
struct WArgs {
    const float* w[3][3];   // [proj][modality]
    const float* b[3][3];
    const float* fcw;
    _Float16* Bt;           // B0 [768][2048] | B1 [768][512] | B2 [768][512]
    float* biasx;           // [3][768]
    _Float16* fcWh;         // [256][256] N-major hi
};

__global__ __launch_bounds__(256) void convert_w_all(WArgs a) {
    const int y = blockIdx.y;
    const int gid = blockIdx.x * 256 + threadIdx.x;
    if (y < 3) {
        const int m = y;
        const int Kdim = (m == 0) ? 2000 : (m == 1 ? 500 : 400);
        const int Kpad = (m == 0) ? 2048 : 512;
        if (gid < NQKV) {
            const int p = gid >> 8, c = gid & 255;
            a.biasx[m * NQKV + gid] = a.b[p][m][c];
        }
        _Float16* dst0 = a.Bt;
        if (m >= 1) dst0 += (size_t)NQKV * 2048;
        if (m == 2) dst0 += (size_t)NQKV * 512;
        const int k8n = Kpad >> 3;
        const int total = NQKV * k8n;
        for (int i = gid; i < total; i += gridDim.x * 256) {
            const int kb = i / NQKV;
            const int n = i - kb * NQKV;
            const int k8 = kb << 3;
            const int p = n >> 8, c = n & 255;
            const float* wsrc = a.w[p][m];
            union { _Float16 h[8]; uint4 v; } hi;
#pragma unroll
            for (int j = 0; j < 8; ++j) {
                float x = (k8 + j < Kdim) ? wsrc[(size_t)(k8 + j) * 256 + c] : 0.f;
                hi.h[j] = (_Float16)x;
            }
            *reinterpret_cast<uint4*>(dst0 + (size_t)n * Kpad + k8) = hi.v;
        }
    } else {
        for (int i = gid; i < 256 * 32; i += gridDim.x * 256) {
            const int n = i & 255;
            const int k8 = (i >> 8) << 3;
            union { _Float16 h[8]; uint4 v; } hi;
#pragma unroll
            for (int j = 0; j < 8; ++j)
                hi.h[j] = (_Float16)a.fcw[(size_t)(k8 + j) * 256 + n];
            *reinterpret_cast<uint4*>(a.fcWh + (size_t)n * 256 + k8) = hi.v;
        }
    }
}

// ---------------------------------------------------------------------------
// K1: fused convert+GEMM.  A staged from X (f32) in registers, split to
// f16 hi|lo planes in LDS; B (hi-only) via global_load_lds, read once per
// macro-step and reused by both MFMA groups (32 MFMA per barrier pair).
// grid (128, 6, 3), block 256 (4 waves, each 64x64 out).
// ---------------------------------------------------------------------------
struct GemmArgs {
    const float* X;
    const _Float16* B[3];
    int ldB[3];     // 2048, 512, 512
    int nk[3];      // 64, 16, 14   (macro-steps of 32 k-elems; all even)
    int Kd[3];      // 2000, 500, 400
    int xoff[3];    // 0, 2000, 2500
};

struct Aregs { float4 v[4]; };

__device__ __forceinline__ void loadA(const float* xbase, int k0, int Kd, int kh,
                                      Aregs& R) {
    if (k0 + 32 <= Kd) {
#pragma unroll
        for (int j = 0; j < 4; ++j)
            R.v[j] = *reinterpret_cast<const float4*>(xbase + k0 + j * 4);
    } else {
#pragma unroll
        for (int j = 0; j < 4; ++j) {
            float4 t = make_float4(0.f, 0.f, 0.f, 0.f);
            const int kb = k0 + kh + j * 4;
            if (kb + 0 < Kd) t.x = xbase[k0 + j * 4 + 0];
            if (kb + 1 < Kd) t.y = xbase[k0 + j * 4 + 1];
            if (kb + 2 < Kd) t.z = xbase[k0 + j * 4 + 2];
            if (kb + 3 < Kd) t.w = xbase[k0 + j * 4 + 3];
            R.v[j] = t;
        }
    }
}

__device__ __forceinline__ void cvtSplit(const Aregs& R, uint4& h0, uint4& h1,
                                         uint4& l0, uint4& l1) {
    union { _Float16 h[8]; uint4 v; } H0, H1, L0, L1;
    float f[16];
#pragma unroll
    for (int j = 0; j < 4; ++j) {
        f[j * 4 + 0] = R.v[j].x; f[j * 4 + 1] = R.v[j].y;
        f[j * 4 + 2] = R.v[j].z; f[j * 4 + 3] = R.v[j].w;
    }
#pragma unroll
    for (int e = 0; e < 8; ++e) {
        _Float16 h = (_Float16)f[e];
        H0.h[e] = h;
        L0.h[e] = (_Float16)(f[e] - (float)h);
    }
#pragma unroll
    for (int e = 0; e < 8; ++e) {
        _Float16 h = (_Float16)f[8 + e];
        H1.h[e] = h;
        L1.h[e] = (_Float16)(f[8 + e] - (float)h);
    }
    h0 = H0.v; h1 = H1.v; l0 = L0.v; l1 = L1.v;
}

__global__ __launch_bounds__(256) void qkv_mfma_all(
    GemmArgs ga, const float* __restrict__ biasx,
    float* __restrict__ Qo, float* __restrict__ Ko, float* __restrict__ Vo) {
    const int z = blockIdx.z;
    const _Float16* __restrict__ Bt = ga.B[z];
    const int ldB = ga.ldB[z];
    const int nkz = ga.nk[z];
    const int Kd = ga.Kd[z];
    const float* __restrict__ bias = biasx + z * NQKV;

    const int row0l = blockIdx.x * BM;
    const int nb = blockIdx.y * BN;
    const int tid = threadIdx.x;
    const int lane = tid & 63;
    const int w = tid >> 6;
    const int wr = w >> 1, wc = w & 1;

    __shared__ alignas(16) _Float16 AsH[BM * BKK];
    __shared__ alignas(16) _Float16 AsL[BM * BKK];
    __shared__ alignas(16) _Float16 Bs[BN * BKK];

    f32x4 acc[4][4];
#pragma unroll
    for (int i = 0; i < 4; ++i)
#pragma unroll
        for (int j = 0; j < 4; ++j) acc[i][j] = (f32x4){0.f, 0.f, 0.f, 0.f};

    // A staging: thread t -> row t>>1, k-half (t&1)*16 (16 f32 -> 16+16 f16)
    const int ar = tid >> 1;
    const int kh = (tid & 1) * 16;
    const float* xbase = ga.X + (size_t)(row0l + ar) * 2900 + ga.xoff[z] + kh;
    uint4* wrH = reinterpret_cast<uint4*>(&AsH[tid * 16]);
    uint4* wrL = reinterpret_cast<uint4*>(&AsL[tid * 16]);

    // B staging (global_load_lds, per-wave): lane -> row l>>2, 16B at (l&3)*8
    const int rs = lane >> 2;
    const int kkv = (lane & 3) * 8;
    const size_t gB0 = (size_t)(nb + w * 16 + rs) * ldB + kkv;
    const size_t gB1 = (size_t)(nb + (w + 4) * 16 + rs) * ldB + kkv;
    _Float16* lB0 = &Bs[(w * 16) * BKK];
    _Float16* lB1 = &Bs[((w + 4) * 16) * BKK];

    // fragment read offsets (row=lane&15, k-block=(lane>>4)*8) — m89-verified
    const int fr = lane & 15;
    const int fk = (lane >> 4) * 8;
    const int aoff0 = (wr * 64 + fr) * BKK + fk;
    const int boff0 = (wc * 64 + fr) * BKK + fk;

    Aregs RA, RB;
    uint4 pAh0, pAh1, pAl0, pAl1;
    uint4 pBh0, pBh1, pBl0, pBl1;

    loadA(xbase, 0, Kd, kh, RA);
    cvtSplit(RA, pAh0, pAh1, pAl0, pAl1);

#pragma unroll 1
    for (int kt = 0; kt < nkz; kt += 2) {
        // ---- macro kt (even): uses pA*, loads kt+1 into RB during MFMA ----
        {
            const int k0 = kt * BKK;
            __syncthreads();                   // prev MFMA reads done
            wrH[0] = pAh0; wrH[1] = pAh1;
            wrL[0] = pAl0; wrL[1] = pAl1;
            gl16(Bt + gB0 + k0, lB0);
            gl16(Bt + gB1 + k0, lB1);
            __syncthreads();                   // staged
            loadA(xbase, (kt + 1) * BKK, Kd, kh, RB);   // hide under MFMA
            f16x8 b[4];
#pragma unroll
            for (int ni = 0; ni < 4; ++ni)
                b[ni] = *reinterpret_cast<const f16x8*>(&Bs[boff0 + ni * 16 * BKK]);
            f16x8 a[4];
#pragma unroll
            for (int mi = 0; mi < 4; ++mi)
                a[mi] = *reinterpret_cast<const f16x8*>(&AsH[aoff0 + mi * 16 * BKK]);
#pragma unroll
            for (int mi = 0; mi < 4; ++mi)
#pragma unroll
                for (int ni = 0; ni < 4; ++ni)
                    acc[mi][ni] = __builtin_amdgcn_mfma_f32_16x16x32_f16(
                        a[mi], b[ni], acc[mi][ni], 0, 0, 0);
#pragma unroll
            for (int mi = 0; mi < 4; ++mi)
                a[mi] = *reinterpret_cast<const f16x8*>(&AsL[aoff0 + mi * 16 * BKK]);
#pragma unroll
            for (int mi = 0; mi < 4; ++mi)
#pragma unroll
                for (int ni = 0; ni < 4; ++ni)
                    acc[mi][ni] = __builtin_amdgcn_mfma_f32_16x16x32_f16(
                        a[mi], b[ni], acc[mi][ni], 0, 0, 0);
            cvtSplit(RB, pBh0, pBh1, pBl0, pBl1);
        }
        // ---- macro kt+1 (odd): uses pB*, loads kt+2 into RA during MFMA ----
        {
            const int k0 = (kt + 1) * BKK;
            __syncthreads();
            wrH[0] = pBh0; wrH[1] = pBh1;
            wrL[0] = pBl0; wrL[1] = pBl1;
            gl16(Bt + gB0 + k0, lB0);
            gl16(Bt + gB1 + k0, lB1);
            __syncthreads();
            if (kt + 2 < nkz) loadA(xbase, (kt + 2) * BKK, Kd, kh, RA);
            f16x8 b[4];
#pragma unroll
            for (int ni = 0; ni < 4; ++ni)
                b[ni] = *reinterpret_cast<const f16x8*>(&Bs[boff0 + ni * 16 * BKK]);
            f16x8 a[4];
#pragma unroll
            for (int mi = 0; mi < 4; ++mi)
                a[mi] = *reinterpret_cast<const f16x8*>(&AsH[aoff0 + mi * 16 * BKK]);
#pragma unroll
            for (int mi = 0; mi < 4; ++mi)
#pragma unroll
                for (int ni = 0; ni < 4; ++ni)
                    acc[mi][ni] = __builtin_amdgcn_mfma_f32_16x16x32_f16(
                        a[mi], b[ni], acc[mi][ni], 0, 0, 0);
#pragma unroll
            for (int mi = 0; mi < 4; ++mi)
                a[mi] = *reinterpret_cast<const f16x8*>(&AsL[aoff0 + mi * 16 * BKK]);
#pragma unroll
            for (int mi = 0; mi < 4; ++mi)
#pragma unroll
                for (int ni = 0; ni < 4; ++ni)
                    acc[mi][ni] = __builtin_amdgcn_mfma_f32_16x16x32_f16(
                        a[mi], b[ni], acc[mi][ni], 0, 0, 0);
            cvtSplit(RA, pAh0, pAh1, pAl0, pAl1);   // garbage on last iter, unused
        }
    }

    // epilogue: C/D layout col=lane&15, row=(lane>>4)*4+j  (m89-verified)
#pragma unroll
    for (int ni = 0; ni < 4; ++ni) {
        const int gc = nb + wc * 64 + ni * 16 + fr;
        const int proj = gc >> 8;
        const int col = gc & 255;
        const float bv = bias[gc];
        float* outp = (proj == 0 ? Qo : proj == 1 ? Ko : Vo);
#pragma unroll
        for (int mi = 0; mi < 4; ++mi) {
            const int gr = row0l + wr * 64 + mi * 16 + (lane >> 4) * 4;
            float* p = outp + (size_t)gr * NQKV + z * 256 + col;
#pragma unroll
            for (int j = 0; j < 4; ++j)
                p[(size_t)j * NQKV] = acc[mi][ni][j] + bv;
        }
    }
}

// ---------------------------------------------------------------------------
// K2: per-sample attention; writes O as f16 hi|lo planes [49152][512].
// ---------------------------------------------------------------------------
__global__ __launch_bounds__(256) void attn_kernel(const float* __restrict__ Q,
                                                   const float* __restrict__ K,
                                                   const float* __restrict__ V,
                                                   _Float16* __restrict__ Of) {
    const int s = blockIdx.x;
    const int t = threadIdx.x;
    __shared__ float qs[NQKV], ks[NQKV], vs[NQKV];
    __shared__ float att[HEADS][3][3];

    const size_t base = (size_t)s * NQKV;
    for (int i = t; i < NQKV; i += 256) {
        qs[i] = Q[base + i];
        ks[i] = K[base + i];
        vs[i] = V[base + i];
    }
    __syncthreads();

    if (t < 72) {
        const int h = t / 9, ij = t % 9, i = ij / 3, j = ij % 3;
        const float* qp = &qs[i * 256 + h * 32];
        const float* kp = &ks[j * 256 + h * 32];
        float sc = 0.f;
#pragma unroll
        for (int d = 0; d < DDK; ++d) sc = fmaf(qp[d], kp[d], sc);
        att[h][i][j] = sc;
    }
    __syncthreads();
    if (t < 24) {
        const int h = t / 3, i = t % 3;
        float s0 = att[h][i][0], s1 = att[h][i][1], s2 = att[h][i][2];
        float r = fabsf(s0) + fabsf(s1) + fabsf(s2);
        r = fmaxf(r, 1e-12f);
        float p0 = s0 / r, p1 = s1 / r, p2 = s2 / r;
        float mx = fmaxf(p0, fmaxf(p1, p2));
        float e0 = expf(p0 - mx), e1 = expf(p1 - mx), e2 = expf(p2 - mx);
        float inv = 1.f / (e0 + e1 + e2);
        att[h][i][0] = e0 * inv;
        att[h][i][1] = e1 * inv;
        att[h][i][2] = e2 * inv;
    }
    __syncthreads();

    const int c = t;
    const int h = c >> 5;
#pragma unroll
    for (int m = 0; m < 3; ++m) {
        float o = att[h][m][0] * vs[c] + att[h][m][1] * vs[256 + c] + att[h][m][2] * vs[512 + c];
        const size_t ob = ((size_t)s * 3 + m) * 512 + c;
        _Float16 oh = (_Float16)o;
        Of[ob] = oh;
        Of[ob + 256] = (_Float16)(o - (float)oh);
    }
}

// ---------------------------------------------------------------------------
// K3: fc via f16x2 MFMA + bias + residual. O[49152][512 hi|lo] @ fcWh[256][256].
// ---------------------------------------------------------------------------
__global__ __launch_bounds__(256) void fc_mfma(const _Float16* __restrict__ O,
                                               const _Float16* __restrict__ Wh,
                                               const float* __restrict__ fcb,
                                               const float* __restrict__ resid,
                                               float* __restrict__ X) {
    const int row0 = blockIdx.x * BM;
    const int nb = blockIdx.y * BN;
    const int tid = threadIdx.x;
    const int lane = tid & 63;
    const int w = tid >> 6;
    const int wr = w >> 1, wc = w & 1;

    __shared__ alignas(16) _Float16 AsH[BM * BKK];
    __shared__ alignas(16) _Float16 AsL[BM * BKK];
    __shared__ alignas(16) _Float16 BsH[BN * BKK];

    f32x4 acc[4][4];
#pragma unroll
    for (int i = 0; i < 4; ++i)
#pragma unroll
        for (int j = 0; j < 4; ++j) acc[i][j] = (f32x4){0.f, 0.f, 0.f, 0.f};

    const int rs = lane >> 2;
    const int kk = (lane & 3) * 8;
    const size_t gA0 = (size_t)(row0 + w * 16 + rs) * 512 + kk;
    const size_t gA1 = (size_t)(row0 + (w + 4) * 16 + rs) * 512 + kk;
    const size_t gB0 = (size_t)(nb + w * 16 + rs) * 256 + kk;
    const size_t gB1 = (size_t)(nb + (w + 4) * 16 + rs) * 256 + kk;
    _Float16* lAH0 = &AsH[w * 512];
    _Float16* lAH1 = &AsH[(w + 4) * 512];
    _Float16* lAL0 = &AsL[w * 512];
    _Float16* lAL1 = &AsL[(w + 4) * 512];
    _Float16* lBH0 = &BsH[w * 512];
    _Float16* lBH1 = &BsH[(w + 4) * 512];

    const int fr = lane & 15;
    const int fk = (lane >> 4) * 8;
    const int aoff0 = (wr * 64 + fr) * BKK + fk;
    const int boff0 = (wc * 64 + fr) * BKK + fk;

#pragma unroll 1
    for (int kt = 0; kt < 8; ++kt) {
        const int k0 = kt * BKK;
        __syncthreads();
        gl16(O + gA0 + k0, lAH0);
        gl16(O + gA1 + k0, lAH1);
        gl16(O + 256 + gA0 + k0, lAL0);
        gl16(O + 256 + gA1 + k0, lAL1);
        gl16(Wh + gB0 + k0, lBH0);
        gl16(Wh + gB1 + k0, lBH1);
        __syncthreads();

        f16x8 ah[4], bh[4];
#pragma unroll
        for (int mi = 0; mi < 4; ++mi)
            ah[mi] = *reinterpret_cast<const f16x8*>(&AsH[aoff0 + mi * 16 * BKK]);
#pragma unroll
        for (int ni = 0; ni < 4; ++ni)
            bh[ni] = *reinterpret_cast<const f16x8*>(&BsH[boff0 + ni * 16 * BKK]);
#pragma unroll
        for (int mi = 0; mi < 4; ++mi)
#pragma unroll
            for (int ni = 0; ni < 4; ++ni)
                acc[mi][ni] = __builtin_amdgcn_mfma_f32_16x16x32_f16(
                    ah[mi], bh[ni], acc[mi][ni], 0, 0, 0);
        {
            f16x8 al[4];
#pragma unroll
            for (int mi = 0; mi < 4; ++mi)
                al[mi] = *reinterpret_cast<const f16x8*>(&AsL[aoff0 + mi * 16 * BKK]);
#pragma unroll
            for (int mi = 0; mi < 4; ++mi)
#pragma unroll
                for (int ni = 0; ni < 4; ++ni)
                    acc[mi][ni] = __builtin_amdgcn_mfma_f32_16x16x32_f16(
                        al[mi], bh[ni], acc[mi][ni], 0, 0, 0);
        }
    }

#pragma unroll
    for (int ni = 0; ni < 4; ++ni) {
        const int gc = nb + wc * 64 + ni * 16 + fr;
        const float bv = fcb[gc];
#pragma unroll
        for (int mi = 0; mi < 4; ++mi) {
            const int gr = row0 + wr * 64 + mi * 16 + (lane >> 4) * 4;
#pragma unroll
            for (int j = 0; j < 4; ++j) {
                const size_t off = (size_t)(gr + j) * 256 + gc;
                X[off] = acc[mi][ni][j] + bv + resid[off];
            }
        }
    }
}

// ---------------------------------------------------------------------------
// K4: LayerNorm (per 256-chunk) + out projection [768]x[768,5].
// ---------------------------------------------------------------------------
__global__ __launch_bounds__(256) void ln_out_kernel(const float* __restrict__ X,
                                                     const float* __restrict__ g,
                                                     const float* __restrict__ bb,
                                                     const float* __restrict__ ow,
                                                     const float* __restrict__ ob,
                                                     float* __restrict__ out) {
    const int s = blockIdx.x;
    const int t = threadIdx.x;
    const int lane = t & 63, wv = t >> 6;
    __shared__ float xr[NQKV];
    __shared__ float red1[4], red2[4];
    __shared__ float cpart[4][NCLASS];

    const size_t base = (size_t)s * NQKV;
    const float gg = g[t];
    const float bbv = bb[t];

    for (int m = 0; m < 3; ++m) {
        float v = X[base + m * 256 + t];
        float s1 = v, s2 = v * v;
#pragma unroll
        for (int off = 32; off > 0; off >>= 1) {
            s1 += __shfl_down(s1, off);
            s2 += __shfl_down(s2, off);
        }
        if (lane == 0) { red1[wv] = s1; red2[wv] = s2; }
        __syncthreads();
        const float tot = red1[0] + red1[1] + red1[2] + red1[3];
        const float tot2 = red2[0] + red2[1] + red2[2] + red2[3];
        const float mu = tot * (1.f / 256.f);
        const float var = tot2 * (1.f / 256.f) - mu * mu;
        const float inv = 1.0f / sqrtf(var + LN_EPS);
        xr[m * 256 + t] = (v - mu) * inv * gg + bbv;
        __syncthreads();
    }

    float p[NCLASS] = {0.f, 0.f, 0.f, 0.f, 0.f};
    for (int i = t; i < NQKV; i += 256) {
        const float xv = xr[i];
#pragma unroll
        for (int c = 0; c < NCLASS; ++c) p[c] = fmaf(xv, ow[i * NCLASS + c], p[c]);
    }
#pragma unroll
    for (int c = 0; c < NCLASS; ++c) {
        float pv = p[c];
#pragma unroll
        for (int off = 32; off > 0; off >>= 1) pv += __shfl_down(pv, off);
        if (lane == 0) cpart[wv][c] = pv;
    }
    __syncthreads();
    if (t < NCLASS)
        out[(size_t)s * NCLASS + t] =
            cpart[0][t] + cpart[1][t] + cpart[2][t] + cpart[3][t] + ob[t];
}

// ---------------------------------------------------------------------------
extern "C" void kernel_launch(void* const* d_in, const int* in_sizes, int n_in,
                              void* d_out, int out_size, void* d_ws, size_t ws_size,
                              hipStream_t stream) {
    const float* x = (const float*)d_in[0];
    WArgs wa;
    int idx = 1;
    for (int p = 0; p < 3; ++p)
        for (int m = 0; m < 3; ++m) {
            wa.w[p][m] = (const float*)d_in[idx++];
            wa.b[p][m] = (const float*)d_in[idx++];
        }
    const float* fc_w = (const float*)d_in[19];
    const float* fc_b = (const float*)d_in[20];
    const float* ln_g = (const float*)d_in[21];
    const float* ln_b = (const float*)d_in[22];
    const float* out_w = (const float*)d_in[23];
    const float* out_b = (const float*)d_in[24];

    float* ws = (float*)d_ws;
    const size_t SZ = (size_t)BATCH * NQKV;
    float* Q = ws;
    float* Kb = ws + SZ;
    float* Vb = ws + 2 * SZ;
    float* biasx = ws + 3 * SZ;                              // [3][768]
    _Float16* Bt = (_Float16*)(biasx + 3 * NQKV);            // 768*(2048+512+512)
    _Float16* fcWh = Bt + (size_t)NQKV * 3072;               // [256][256]
    _Float16* Of = fcWh + 256 * 256;                         // [49152][512] hi|lo

    wa.fcw = fc_w; wa.Bt = Bt; wa.biasx = biasx; wa.fcWh = fcWh;

    float* X = Q;                 // alias: Q dead after attn

    convert_w_all<<<dim3(768, 4), 256, 0, stream>>>(wa);

    GemmArgs ga;
    ga.X = x;
    ga.B[0] = Bt;
    ga.B[1] = Bt + (size_t)NQKV * 2048;
    ga.B[2] = Bt + (size_t)NQKV * 2048 + (size_t)NQKV * 512;
    ga.ldB[0] = 2048; ga.ldB[1] = 512; ga.ldB[2] = 512;
    ga.nk[0] = 64; ga.nk[1] = 16; ga.nk[2] = 14;
    ga.Kd[0] = 2000; ga.Kd[1] = 500; ga.Kd[2] = 400;
    ga.xoff[0] = 0; ga.xoff[1] = 2000; ga.xoff[2] = 2500;

    dim3 g(BATCH / BM, NQKV / BN, 3);
    qkv_mfma_all<<<g, 256, 0, stream>>>(ga, biasx, Q, Kb, Vb);

    attn_kernel<<<BATCH, 256, 0, stream>>>(Q, Kb, Vb, Of);

    fc_mfma<<<dim3((BATCH * 3) / BM, 2), 256, 0, stream>>>(Of, fcWh, fc_b, Vb, X);

    ln_out_kernel<<<BATCH, 256, 0, stream>>>(X, ln_g, ln_b, out_w, out_b, (float*)d_out);
}

// Round 8
// 645.701 us; speedup vs baseline: 1.9188x; 1.0142x over previous
//
#include <hip/hip_runtime.h>
#include <hip/hip_bf16.h>

#define BATCH 16384
#define HEADS 8
#define DDK 32
#define NQKV 768
#define NCLASS 5
#define LN_EPS 1e-6f

#define BM 128
#define BN 128
#define BKK 32

typedef _Float16 f16x8 __attribute__((ext_vector_type(8)));
typedef float f32x4 __attribute__((ext_vector_type(4)));

__device__ __forceinline__ void gl16(const void* g, void* l) {
    __builtin_amdgcn_global_load_lds(
        (const __attribute__((address_space(1))) unsigned int*)g,
        (__attribute__((address_space(3))) unsigned int*)l, 16, 0, 0);
}

// ---------------------------------------------------------------------------
// convert weights: qkv N-major hi-only per modality + fc_w hi-only N-major
// grid (768, 4): y=0..2 -> modality, y=3 -> fc_w
// ---------------------------------------------------------------------------
struct WArgs {
    const float* w[3][3];   // [proj][modality]
    const float* b[3][3];
    const float* fcw;
    _Float16* Bt;           // B0 [768][2048] | B1 [768][512] | B2 [768][512]
    float* biasx;           // [3][768]
    _Float16* fcWh;         // [256][256] N-major hi
};

__global__ __launch_bounds__(256) void convert_w_all(WArgs a) {
    const int y = blockIdx.y;
    const int gid = blockIdx.x * 256 + threadIdx.x;
    if (y < 3) {
        const int m = y;
        const int Kdim = (m == 0) ? 2000 : (m == 1 ? 500 : 400);
        const int Kpad = (m == 0) ? 2048 : 512;
        if (gid < NQKV) {
            const int p = gid >> 8, c = gid & 255;
            a.biasx[m * NQKV + gid] = a.b[p][m][c];
        }
        _Float16* dst0 = a.Bt;
        if (m >= 1) dst0 += (size_t)NQKV * 2048;
        if (m == 2) dst0 += (size_t)NQKV * 512;
        const int k8n = Kpad >> 3;
        const int total = NQKV * k8n;
        for (int i = gid; i < total; i += gridDim.x * 256) {
            const int kb = i / NQKV;
            const int n = i - kb * NQKV;
            const int k8 = kb << 3;
            const int p = n >> 8, c = n & 255;
            const float* wsrc = a.w[p][m];
            union { _Float16 h[8]; uint4 v; } hi;
#pragma unroll
            for (int j = 0; j < 8; ++j) {
                float x = (k8 + j < Kdim) ? wsrc[(size_t)(k8 + j) * 256 + c] : 0.f;
                hi.h[j] = (_Float16)x;
            }
            *reinterpret_cast<uint4*>(dst0 + (size_t)n * Kpad + k8) = hi.v;
        }
    } else {
        for (int i = gid; i < 256 * 32; i += gridDim.x * 256) {
            const int n = i & 255;
            const int k8 = (i >> 8) << 3;
            union { _Float16 h[8]; uint4 v; } hi;
#pragma unroll
            for (int j = 0; j < 8; ++j)
                hi.h[j] = (_Float16)a.fcw[(size_t)(k8 + j) * 256 + n];
            *reinterpret_cast<uint4*>(a.fcWh + (size_t)n * 256 + k8) = hi.v;
        }
    }
}

// ---------------------------------------------------------------------------
// K1: fused convert+GEMM (unchanged from R7).
// ---------------------------------------------------------------------------
struct GemmArgs {
    const float* X;
    const _Float16* B[3];
    int ldB[3];     // 2048, 512, 512
    int nk[3];      // 64, 16, 14
    int Kd[3];      // 2000, 500, 400
    int xoff[3];    // 0, 2000, 2500
};

struct Aregs { float4 v[4]; };

__device__ __forceinline__ void loadA(const float* xbase, int k0, int Kd, int kh,
                                      Aregs& R) {
    if (k0 + 32 <= Kd) {
#pragma unroll
        for (int j = 0; j < 4; ++j)
            R.v[j] = *reinterpret_cast<const float4*>(xbase + k0 + j * 4);
    } else {
#pragma unroll
        for (int j = 0; j < 4; ++j) {
            float4 t = make_float4(0.f, 0.f, 0.f, 0.f);
            const int kb = k0 + kh + j * 4;
            if (kb + 0 < Kd) t.x = xbase[k0 + j * 4 + 0];
            if (kb + 1 < Kd) t.y = xbase[k0 + j * 4 + 1];
            if (kb + 2 < Kd) t.z = xbase[k0 + j * 4 + 2];
            if (kb + 3 < Kd) t.w = xbase[k0 + j * 4 + 3];
            R.v[j] = t;
        }
    }
}

__device__ __forceinline__ void cvtSplit(const Aregs& R, uint4& h0, uint4& h1,
                                         uint4& l0, uint4& l1) {
    union { _Float16 h[8]; uint4 v; } H0, H1, L0, L1;
    float f[16];
#pragma unroll
    for (int j = 0; j < 4; ++j) {
        f[j * 4 + 0] = R.v[j].x; f[j * 4 + 1] = R.v[j].y;
        f[j * 4 + 2] = R.v[j].z; f[j * 4 + 3] = R.v[j].w;
    }
#pragma unroll
    for (int e = 0; e < 8; ++e) {
        _Float16 h = (_Float16)f[e];
        H0.h[e] = h;
        L0.h[e] = (_Float16)(f[e] - (float)h);
    }
#pragma unroll
    for (int e = 0; e < 8; ++e) {
        _Float16 h = (_Float16)f[8 + e];
        H1.h[e] = h;
        L1.h[e] = (_Float16)(f[8 + e] - (float)h);
    }
    h0 = H0.v; h1 = H1.v; l0 = L0.v; l1 = L1.v;
}

__global__ __launch_bounds__(256) void qkv_mfma_all(
    GemmArgs ga, const float* __restrict__ biasx,
    float* __restrict__ Qo, float* __restrict__ Ko, float* __restrict__ Vo) {
    const int z = blockIdx.z;
    const _Float16* __restrict__ Bt = ga.B[z];
    const int ldB = ga.ldB[z];
    const int nkz = ga.nk[z];
    const int Kd = ga.Kd[z];
    const float* __restrict__ bias = biasx + z * NQKV;

    const int row0l = blockIdx.x * BM;
    const int nb = blockIdx.y * BN;
    const int tid = threadIdx.x;
    const int lane = tid & 63;
    const int w = tid >> 6;
    const int wr = w >> 1, wc = w & 1;

    __shared__ alignas(16) _Float16 AsH[BM * BKK];
    __shared__ alignas(16) _Float16 AsL[BM * BKK];
    __shared__ alignas(16) _Float16 Bs[BN * BKK];

    f32x4 acc[4][4];
#pragma unroll
    for (int i = 0; i < 4; ++i)
#pragma unroll
        for (int j = 0; j < 4; ++j) acc[i][j] = (f32x4){0.f, 0.f, 0.f, 0.f};

    const int ar = tid >> 1;
    const int kh = (tid & 1) * 16;
    const float* xbase = ga.X + (size_t)(row0l + ar) * 2900 + ga.xoff[z] + kh;
    uint4* wrH = reinterpret_cast<uint4*>(&AsH[tid * 16]);
    uint4* wrL = reinterpret_cast<uint4*>(&AsL[tid * 16]);

    const int rs = lane >> 2;
    const int kkv = (lane & 3) * 8;
    const size_t gB0 = (size_t)(nb + w * 16 + rs) * ldB + kkv;
    const size_t gB1 = (size_t)(nb + (w + 4) * 16 + rs) * ldB + kkv;
    _Float16* lB0 = &Bs[(w * 16) * BKK];
    _Float16* lB1 = &Bs[((w + 4) * 16) * BKK];

    const int fr = lane & 15;
    const int fk = (lane >> 4) * 8;
    const int aoff0 = (wr * 64 + fr) * BKK + fk;
    const int boff0 = (wc * 64 + fr) * BKK + fk;

    Aregs RA, RB;
    uint4 pAh0, pAh1, pAl0, pAl1;
    uint4 pBh0, pBh1, pBl0, pBl1;

    loadA(xbase, 0, Kd, kh, RA);
    cvtSplit(RA, pAh0, pAh1, pAl0, pAl1);

#pragma unroll 1
    for (int kt = 0; kt < nkz; kt += 2) {
        {
            const int k0 = kt * BKK;
            __syncthreads();
            wrH[0] = pAh0; wrH[1] = pAh1;
            wrL[0] = pAl0; wrL[1] = pAl1;
            gl16(Bt + gB0 + k0, lB0);
            gl16(Bt + gB1 + k0, lB1);
            __syncthreads();
            loadA(xbase, (kt + 1) * BKK, Kd, kh, RB);
            f16x8 b[4];
#pragma unroll
            for (int ni = 0; ni < 4; ++ni)
                b[ni] = *reinterpret_cast<const f16x8*>(&Bs[boff0 + ni * 16 * BKK]);
            f16x8 a[4];
#pragma unroll
            for (int mi = 0; mi < 4; ++mi)
                a[mi] = *reinterpret_cast<const f16x8*>(&AsH[aoff0 + mi * 16 * BKK]);
#pragma unroll
            for (int mi = 0; mi < 4; ++mi)
#pragma unroll
                for (int ni = 0; ni < 4; ++ni)
                    acc[mi][ni] = __builtin_amdgcn_mfma_f32_16x16x32_f16(
                        a[mi], b[ni], acc[mi][ni], 0, 0, 0);
#pragma unroll
            for (int mi = 0; mi < 4; ++mi)
                a[mi] = *reinterpret_cast<const f16x8*>(&AsL[aoff0 + mi * 16 * BKK]);
#pragma unroll
            for (int mi = 0; mi < 4; ++mi)
#pragma unroll
                for (int ni = 0; ni < 4; ++ni)
                    acc[mi][ni] = __builtin_amdgcn_mfma_f32_16x16x32_f16(
                        a[mi], b[ni], acc[mi][ni], 0, 0, 0);
            cvtSplit(RB, pBh0, pBh1, pBl0, pBl1);
        }
        {
            const int k0 = (kt + 1) * BKK;
            __syncthreads();
            wrH[0] = pBh0; wrH[1] = pBh1;
            wrL[0] = pBl0; wrL[1] = pBl1;
            gl16(Bt + gB0 + k0, lB0);
            gl16(Bt + gB1 + k0, lB1);
            __syncthreads();
            if (kt + 2 < nkz) loadA(xbase, (kt + 2) * BKK, Kd, kh, RA);
            f16x8 b[4];
#pragma unroll
            for (int ni = 0; ni < 4; ++ni)
                b[ni] = *reinterpret_cast<const f16x8*>(&Bs[boff0 + ni * 16 * BKK]);
            f16x8 a[4];
#pragma unroll
            for (int mi = 0; mi < 4; ++mi)
                a[mi] = *reinterpret_cast<const f16x8*>(&AsH[aoff0 + mi * 16 * BKK]);
#pragma unroll
            for (int mi = 0; mi < 4; ++mi)
#pragma unroll
                for (int ni = 0; ni < 4; ++ni)
                    acc[mi][ni] = __builtin_amdgcn_mfma_f32_16x16x32_f16(
                        a[mi], b[ni], acc[mi][ni], 0, 0, 0);
#pragma unroll
            for (int mi = 0; mi < 4; ++mi)
                a[mi] = *reinterpret_cast<const f16x8*>(&AsL[aoff0 + mi * 16 * BKK]);
#pragma unroll
            for (int mi = 0; mi < 4; ++mi)
#pragma unroll
                for (int ni = 0; ni < 4; ++ni)
                    acc[mi][ni] = __builtin_amdgcn_mfma_f32_16x16x32_f16(
                        a[mi], b[ni], acc[mi][ni], 0, 0, 0);
            cvtSplit(RA, pAh0, pAh1, pAl0, pAl1);
        }
    }

#pragma unroll
    for (int ni = 0; ni < 4; ++ni) {
        const int gc = nb + wc * 64 + ni * 16 + fr;
        const int proj = gc >> 8;
        const int col = gc & 255;
        const float bv = bias[gc];
        float* outp = (proj == 0 ? Qo : proj == 1 ? Ko : Vo);
#pragma unroll
        for (int mi = 0; mi < 4; ++mi) {
            const int gr = row0l + wr * 64 + mi * 16 + (lane >> 4) * 4;
            float* p = outp + (size_t)gr * NQKV + z * 256 + col;
#pragma unroll
            for (int j = 0; j < 4; ++j)
                p[(size_t)j * NQKV] = acc[mi][ni][j] + bv;
        }
    }
}

// ---------------------------------------------------------------------------
// K2 (NEW): fused attention + fc(f16x2 MFMA) + residual + LayerNorm + out-proj.
// 4 samples per block, grid 16384/4 = 4096, block 256 (4 waves).
// Intermediates O and X never leave LDS.
// ---------------------------------------------------------------------------
__global__ __launch_bounds__(256) void attn_fc_ln_out(
    const float* __restrict__ Q, const float* __restrict__ K,
    const float* __restrict__ V, const _Float16* __restrict__ Wh,
    const float* __restrict__ fcb, const float* __restrict__ lng,
    const float* __restrict__ lnb, const float* __restrict__ ow,
    const float* __restrict__ ob, float* __restrict__ out) {
    const int s0 = blockIdx.x * 4;
    const int t = threadIdx.x;
    const int lane = t & 63;
    const int w = t >> 6;

    // QK region (24KB+): Qs[0..3071] | Ks[3072..6143]; reused as Ohi/Olo f16
    // planes (rows 0..15 x 256 k, XOR-swizzled); reused again as Xs[16][260].
    __shared__ alignas(16) float QK[6656];
    __shared__ float Vs[3072];
    __shared__ float att[288];          // [s][h][qi][kj] = s*72+h*9+qi*3+kj
    __shared__ float mu_s[16], inv_s[16];

    // ---- P0: load Q,K,V rows for 4 samples (fully coalesced) ----
    const size_t qb = (size_t)s0 * NQKV;
    for (int i = t; i < 3072; i += 256) {
        QK[i]        = Q[qb + i];
        QK[3072 + i] = K[qb + i];
        Vs[i]        = V[qb + i];
    }
    __syncthreads();

    // ---- P1: scores (global-min scale + TEMP cancel in L1 norm) ----
    for (int i = t; i < 288; i += 256) {
        const int s = i / 72;
        const int e = i - s * 72;
        const int h = e / 9;
        const int e9 = e - h * 9;
        const int qi = e9 / 3;
        const int kj = e9 - qi * 3;
        const float* qp = &QK[s * NQKV + qi * 256 + h * 32];
        const float* kp = &QK[3072 + s * NQKV + kj * 256 + h * 32];
        float sc = 0.f;
#pragma unroll
        for (int d = 0; d < DDK; ++d) sc = fmaf(qp[d], kp[d], sc);
        att[i] = sc;
    }
    __syncthreads();

    // ---- P2: L1-normalize + softmax per (s,h,qi) row ----
    if (t < 96) {
        const int s = t / 24;
        const int e = t - s * 24;
        const int h = e / 3;
        const int qi = e - h * 3;
        float* ap = &att[s * 72 + h * 9 + qi * 3];
        float s0v = ap[0], s1v = ap[1], s2v = ap[2];
        float r = fabsf(s0v) + fabsf(s1v) + fabsf(s2v);
        r = fmaxf(r, 1e-12f);
        float p0 = s0v / r, p1 = s1v / r, p2 = s2v / r;
        float mx = fmaxf(p0, fmaxf(p1, p2));
        float e0 = expf(p0 - mx), e1 = expf(p1 - mx), e2 = expf(p2 - mx);
        float inv = 1.f / (e0 + e1 + e2);
        ap[0] = e0 * inv; ap[1] = e1 * inv; ap[2] = e2 * inv;
    }
    __syncthreads();

    // ---- P3: O = att @ V, split to f16 hi|lo in swizzled LDS planes ----
    // Ohi at byte 0 of QK, Olo at byte 8192. Row ra = s*3+m (12 real, 4 zero).
    {
        char* OhiB = reinterpret_cast<char*>(&QK[0]);
        char* OloB = reinterpret_cast<char*>(&QK[2048]);
        const int c = t;
        const int h = c >> 5;
#pragma unroll
        for (int ra = 0; ra < 16; ++ra) {
            float o = 0.f;
            if (ra < 12) {
                const int s = ra / 3, m = ra - (ra / 3) * 3;
                const float* ap = &att[s * 72 + h * 9 + m * 3];
                o = ap[0] * Vs[s * NQKV + c] + ap[1] * Vs[s * NQKV + 256 + c] +
                    ap[2] * Vs[s * NQKV + 512 + c];
            }
            _Float16 oh = (_Float16)o;
            _Float16 ol = (_Float16)(o - (float)oh);
            const int bo = (ra * 512 + c * 2) ^ ((ra & 7) << 4);
            *reinterpret_cast<_Float16*>(OhiB + bo) = oh;
            *reinterpret_cast<_Float16*>(OloB + bo) = ol;
        }
    }
    __syncthreads();

    // ---- P4: fc via f16x2 MFMA. Wave w owns n-range [w*64, w*64+64). ----
    f32x4 acc[4];
#pragma unroll
    for (int nb = 0; nb < 4; ++nb) acc[nb] = (f32x4){0.f, 0.f, 0.f, 0.f};
    const int fr = lane & 15;
    const int fk = (lane >> 4) * 8;
    {
        const char* OhiB = reinterpret_cast<const char*>(&QK[0]);
        const char* OloB = reinterpret_cast<const char*>(&QK[2048]);
#pragma unroll
        for (int ks = 0; ks < 8; ++ks) {
            const int abo = (fr * 512 + (ks * 32 + fk) * 2) ^ ((fr & 7) << 4);
            f16x8 ah = *reinterpret_cast<const f16x8*>(OhiB + abo);
            f16x8 al = *reinterpret_cast<const f16x8*>(OloB + abo);
#pragma unroll
            for (int nb = 0; nb < 4; ++nb) {
                const _Float16* bp =
                    &Wh[(size_t)(w * 64 + nb * 16 + fr) * 256 + ks * 32 + fk];
                f16x8 b = *reinterpret_cast<const f16x8*>(bp);
                acc[nb] = __builtin_amdgcn_mfma_f32_16x16x32_f16(ah, b, acc[nb], 0, 0, 0);
                acc[nb] = __builtin_amdgcn_mfma_f32_16x16x32_f16(al, b, acc[nb], 0, 0, 0);
            }
        }
    }
    __syncthreads();   // all waves done reading Ohi/Olo before Xs overwrite

    // epilogue: + fc_b + residual(V); write X rows<12 into Xs[16][260]
    {
        float* Xs = &QK[0];
#pragma unroll
        for (int nb = 0; nb < 4; ++nb) {
            const int col = w * 64 + nb * 16 + fr;
            const float bv = fcb[col];
#pragma unroll
            for (int j = 0; j < 4; ++j) {
                const int row = (lane >> 4) * 4 + j;
                if (row < 12) {
                    const int s = row / 3, m = row - (row / 3) * 3;
                    const float xn =
                        acc[nb][j] + bv + Vs[s * NQKV + m * 256 + col];
                    Xs[row * 260 + col] = xn;
                }
            }
        }
    }
    __syncthreads();

    // ---- P5: LayerNorm stats per row (wave w -> rows w*3..w*3+2) ----
    {
        const float* Xs = &QK[0];
#pragma unroll
        for (int rr = 0; rr < 3; ++rr) {
            const int row = w * 3 + rr;
            float s1 = 0.f, s2 = 0.f;
#pragma unroll
            for (int kk = 0; kk < 4; ++kk) {
                const float v = Xs[row * 260 + lane + kk * 64];
                s1 += v; s2 += v * v;
            }
#pragma unroll
            for (int off = 32; off > 0; off >>= 1) {
                s1 += __shfl_down(s1, off);
                s2 += __shfl_down(s2, off);
            }
            if (lane == 0) {
                const float mu = s1 * (1.f / 256.f);
                const float var = s2 * (1.f / 256.f) - mu * mu;
                mu_s[row] = mu;
                inv_s[row] = 1.0f / sqrtf(var + LN_EPS);
            }
        }
    }
    __syncthreads();

    // ---- P6: normalize + out-proj; wave w handles sample s0+w ----
    {
        const float* Xs = &QK[0];
        const int si = w;
        float p[NCLASS] = {0.f, 0.f, 0.f, 0.f, 0.f};
#pragma unroll
        for (int m = 0; m < 3; ++m) {
            const int row = si * 3 + m;
            const float mu = mu_s[row], inv = inv_s[row];
#pragma unroll
            for (int kk = 0; kk < 4; ++kk) {
                const int col = lane + kk * 64;
                const float xr =
                    (Xs[row * 260 + col] - mu) * inv * lng[col] + lnb[col];
                const float* owp = &ow[(size_t)(m * 256 + col) * NCLASS];
#pragma unroll
                for (int c = 0; c < NCLASS; ++c) p[c] = fmaf(xr, owp[c], p[c]);
            }
        }
#pragma unroll
        for (int c = 0; c < NCLASS; ++c) {
#pragma unroll
            for (int off = 32; off > 0; off >>= 1) p[c] += __shfl_down(p[c], off);
        }
        if (lane == 0) {
#pragma unroll
            for (int c = 0; c < NCLASS; ++c)
                out[(size_t)(s0 + si) * NCLASS + c] = p[c] + ob[c];
        }
    }
}

// ---------------------------------------------------------------------------
extern "C" void kernel_launch(void* const* d_in, const int* in_sizes, int n_in,
                              void* d_out, int out_size, void* d_ws, size_t ws_size,
                              hipStream_t stream) {
    const float* x = (const float*)d_in[0];
    WArgs wa;
    int idx = 1;
    for (int p = 0; p < 3; ++p)
        for (int m = 0; m < 3; ++m) {
            wa.w[p][m] = (const float*)d_in[idx++];
            wa.b[p][m] = (const float*)d_in[idx++];
        }
    const float* fc_w = (const float*)d_in[19];
    const float* fc_b = (const float*)d_in[20];
    const float* ln_g = (const float*)d_in[21];
    const float* ln_b = (const float*)d_in[22];
    const float* out_w = (const float*)d_in[23];
    const float* out_b = (const float*)d_in[24];

    float* ws = (float*)d_ws;
    const size_t SZ = (size_t)BATCH * NQKV;
    float* Q = ws;
    float* Kb = ws + SZ;
    float* Vb = ws + 2 * SZ;
    float* biasx = ws + 3 * SZ;                              // [3][768]
    _Float16* Bt = (_Float16*)(biasx + 3 * NQKV);            // 768*(2048+512+512)
    _Float16* fcWh = Bt + (size_t)NQKV * 3072;               // [256][256]

    wa.fcw = fc_w; wa.Bt = Bt; wa.biasx = biasx; wa.fcWh = fcWh;

    convert_w_all<<<dim3(768, 4), 256, 0, stream>>>(wa);

    GemmArgs ga;
    ga.X = x;
    ga.B[0] = Bt;
    ga.B[1] = Bt + (size_t)NQKV * 2048;
    ga.B[2] = Bt + (size_t)NQKV * 2048 + (size_t)NQKV * 512;
    ga.ldB[0] = 2048; ga.ldB[1] = 512; ga.ldB[2] = 512;
    ga.nk[0] = 64; ga.nk[1] = 16; ga.nk[2] = 14;
    ga.Kd[0] = 2000; ga.Kd[1] = 500; ga.Kd[2] = 400;
    ga.xoff[0] = 0; ga.xoff[1] = 2000; ga.xoff[2] = 2500;

    dim3 g(BATCH / BM, NQKV / BN, 3);
    qkv_mfma_all<<<g, 256, 0, stream>>>(ga, biasx, Q, Kb, Vb);

    attn_fc_ln_out<<<BATCH / 4, 256, 0, stream>>>(
        Q, Kb, Vb, fcWh, fc_b, ln_g, ln_b, out_w, out_b, (float*)d_out);
}